// Round 1
// baseline (1450.859 us; speedup 1.0000x reference)
//
#include <hip/hip_runtime.h>

#define NN 100000
#define NE 3200000
#define IN_DIM 512
#define HID 256
#define OUTD 64

// ---------------- CSR build ----------------

__global__ void count_kernel(const int* __restrict__ src, int* __restrict__ counts, int E) {
    int e = blockIdx.x * blockDim.x + threadIdx.x;
    if (e < E) atomicAdd(&counts[src[e]], 1);
}

__global__ __launch_bounds__(1024) void scan_kernel(const int4* __restrict__ counts4,
                                                    int* __restrict__ offsets,
                                                    int* __restrict__ cursor,
                                                    int n4, int n) {
    __shared__ int wsum[16];
    __shared__ int chunk_base;
    if (threadIdx.x == 0) chunk_base = 0;
    __syncthreads();
    const int lane = threadIdx.x & 63;
    const int wid  = threadIdx.x >> 6;
    const int iters = (n4 + 1023) / 1024;
    for (int it = 0; it < iters; ++it) {
        int i4 = it * 1024 + threadIdx.x;
        int4 c = make_int4(0, 0, 0, 0);
        if (i4 < n4) c = counts4[i4];
        int s = c.x + c.y + c.z + c.w;
        int x = s;
        #pragma unroll
        for (int d = 1; d < 64; d <<= 1) {
            int y = __shfl_up(x, d);
            if (lane >= d) x += y;
        }
        if (lane == 63) wsum[wid] = x;
        __syncthreads();
        if (threadIdx.x < 16) {
            int t = wsum[threadIdx.x];
            #pragma unroll
            for (int d = 1; d < 16; d <<= 1) {
                int y = __shfl_up(t, d);
                if (lane >= d) t += y;
            }
            wsum[threadIdx.x] = t;
        }
        __syncthreads();
        int excl = x - s + (wid ? wsum[wid - 1] : 0);
        int base = chunk_base;
        if (i4 < n4) {
            int4 o;
            o.x = base + excl;
            o.y = o.x + c.x;
            o.z = o.y + c.y;
            o.w = o.z + c.z;
            ((int4*)offsets)[i4] = o;
            ((int4*)cursor)[i4]  = o;
        }
        __syncthreads();
        if (threadIdx.x == 0) chunk_base += wsum[15];
        __syncthreads();
    }
    if (threadIdx.x == 0) offsets[n] = chunk_base;
}

__global__ void scatter_kernel(const int* __restrict__ src, const int* __restrict__ dst,
                               const float* __restrict__ val, int* __restrict__ cursor,
                               int2* __restrict__ pairs, int E) {
    int e = blockIdx.x * blockDim.x + threadIdx.x;
    if (e < E) {
        int s = src[e];
        int p = atomicAdd(&cursor[s], 1);
        pairs[p] = make_int2(dst[e], __float_as_int(val[e]));
    }
}

// ---------------- f32 tiled GEMM: C[M,N] = A[M,K] @ B[K,N] ----------------
// 64x64 tile, BK=32, 256 threads, 4x4 microtile.

__global__ __launch_bounds__(256) void gemm64(const float* __restrict__ A,
                                              const float* __restrict__ B,
                                              float* __restrict__ C,
                                              int M, int N, int K) {
    __shared__ float As[32][68];   // transposed: As[k][m], pad 68 keeps float4 16B-aligned
    __shared__ float Bs[32][64];
    const int m0 = blockIdx.x * 64;
    const int n0 = blockIdx.y * 64;
    const int t  = threadIdx.x;
    const int tm = t & 15, tn = t >> 4;
    float acc[4][4] = {};
    for (int k0 = 0; k0 < K; k0 += 32) {
        // stage A: 64 rows x 32 k, transposed into As[k][m]
        {
            int ml = t >> 3;          // 0..31
            int kl = (t & 7) * 4;     // 0,4,...,28
            #pragma unroll
            for (int p = 0; p < 2; ++p) {
                int m = m0 + ml + p * 32;
                float4 v = make_float4(0.f, 0.f, 0.f, 0.f);
                if (m < M) v = *(const float4*)(A + (size_t)m * K + k0 + kl);
                As[kl + 0][ml + p * 32] = v.x;
                As[kl + 1][ml + p * 32] = v.y;
                As[kl + 2][ml + p * 32] = v.z;
                As[kl + 3][ml + p * 32] = v.w;
            }
        }
        // stage B: 32 k x 64 n
        {
            int kl = t >> 4;          // 0..15
            int nl = (t & 15) * 4;    // 0..60
            #pragma unroll
            for (int p = 0; p < 2; ++p) {
                float4 v = *(const float4*)(B + (size_t)(k0 + kl + p * 16) * N + n0 + nl);
                *(float4*)&Bs[kl + p * 16][nl] = v;
            }
        }
        __syncthreads();
        #pragma unroll
        for (int k = 0; k < 32; ++k) {
            float4 a = *(const float4*)&As[k][tm * 4];
            float4 b = *(const float4*)&Bs[k][tn * 4];
            float av[4] = {a.x, a.y, a.z, a.w};
            float bv[4] = {b.x, b.y, b.z, b.w};
            #pragma unroll
            for (int i = 0; i < 4; ++i)
                #pragma unroll
                for (int j = 0; j < 4; ++j)
                    acc[i][j] = fmaf(av[i], bv[j], acc[i][j]);
        }
        __syncthreads();
    }
    #pragma unroll
    for (int i = 0; i < 4; ++i) {
        int m = m0 + tm * 4 + i;
        if (m < M) {
            float4 o = make_float4(acc[i][0], acc[i][1], acc[i][2], acc[i][3]);
            *(float4*)(C + (size_t)m * N + n0 + tn * 4) = o;
        }
    }
}

// ---------------- SpMM: out[i][:] = sum_{e: src=i} val_e * dense[dst_e][:] ----------------
// One wave per node. D=256: lane handles float4. D=64: lane handles 1 float.

__global__ __launch_bounds__(256) void spmm_relu256(const int* __restrict__ offs,
                                                    const int2* __restrict__ pairs,
                                                    const float* __restrict__ dense,
                                                    float* __restrict__ out, int n) {
    int node = blockIdx.x * 4 + (threadIdx.x >> 6);
    if (node >= n) return;
    int lane = threadIdx.x & 63;
    int beg = offs[node], end = offs[node + 1];
    float4 acc = make_float4(0.f, 0.f, 0.f, 0.f);
    for (int k = beg; k < end; ++k) {
        int2 pr = pairs[k];
        float v = __int_as_float(pr.y);
        float4 p = *(const float4*)(dense + (size_t)pr.x * 256 + lane * 4);
        acc.x = fmaf(v, p.x, acc.x);
        acc.y = fmaf(v, p.y, acc.y);
        acc.z = fmaf(v, p.z, acc.z);
        acc.w = fmaf(v, p.w, acc.w);
    }
    acc.x = fmaxf(acc.x, 0.f);
    acc.y = fmaxf(acc.y, 0.f);
    acc.z = fmaxf(acc.z, 0.f);
    acc.w = fmaxf(acc.w, 0.f);
    *(float4*)(out + (size_t)node * 256 + lane * 4) = acc;
}

__global__ __launch_bounds__(256) void spmm64(const int* __restrict__ offs,
                                              const int2* __restrict__ pairs,
                                              const float* __restrict__ dense,
                                              float* __restrict__ out, int n) {
    int node = blockIdx.x * 4 + (threadIdx.x >> 6);
    if (node >= n) return;
    int lane = threadIdx.x & 63;
    int beg = offs[node], end = offs[node + 1];
    float acc = 0.f;
    for (int k = beg; k < end; ++k) {
        int2 pr = pairs[k];
        acc = fmaf(__int_as_float(pr.y), dense[(size_t)pr.x * 64 + lane], acc);
    }
    out[(size_t)node * 64 + lane] = acc;
}

// ---------------- launch ----------------

extern "C" void kernel_launch(void* const* d_in, const int* in_sizes, int n_in,
                              void* d_out, int out_size, void* d_ws, size_t ws_size,
                              hipStream_t stream) {
    const float* x    = (const float*)d_in[0];
    const int*   esrc = (const int*)d_in[1];
    const int*   edst = (const int*)d_in[2];
    const float* eval = (const float*)d_in[3];
    const float* w1   = (const float*)d_in[4];
    const float* w2   = (const float*)d_in[5];
    float* out = (float*)d_out;

    char* ws = (char*)d_ws;
    float* pre    = (float*)(ws + 0);            // 100000*256*4 = 102,400,000
    float* h      = (float*)(ws + 102400000);    // 102,400,000
    int2*  pairs  = (int2*)(ws + 204800000);     // 3.2M * 8 = 25,600,000
    int*   counts = (int*)(ws + 230400000);      // 400,000
    int*   offs   = (int*)(ws + 230800000);      // 400,004 (padded)
    int*   cursor = (int*)(ws + 231200128);      // 400,000
    float* h2 = pre;                             // pre is dead after spmm1; alias

    hipMemsetAsync(counts, 0, NN * sizeof(int), stream);
    count_kernel<<<(NE + 255) / 256, 256, 0, stream>>>(esrc, counts, NE);
    scan_kernel<<<1, 1024, 0, stream>>>((const int4*)counts, offs, cursor, NN / 4, NN);
    scatter_kernel<<<(NE + 255) / 256, 256, 0, stream>>>(esrc, edst, eval, cursor, pairs, NE);

    dim3 g1((NN + 63) / 64, HID / 64);
    gemm64<<<g1, 256, 0, stream>>>(x, w1, pre, NN, HID, IN_DIM);

    spmm_relu256<<<(NN + 3) / 4, 256, 0, stream>>>(offs, pairs, pre, h, NN);

    dim3 g2((NN + 63) / 64, OUTD / 64);
    gemm64<<<g2, 256, 0, stream>>>(h, w2, h2, NN, OUTD, HID);

    spmm64<<<(NN + 3) / 4, 256, 0, stream>>>(offs, pairs, h2, out, NN);
}

// Round 2
// 1062.958 us; speedup vs baseline: 1.3649x; 1.3649x over previous
//
#include <hip/hip_runtime.h>

#define NN 100000
#define NE 3200000
#define IN_DIM 512
#define HID 256
#define OUTD 64

typedef _Float16 f16x8 __attribute__((ext_vector_type(8)));
typedef _Float16 f16x4 __attribute__((ext_vector_type(4)));
typedef float f32x4 __attribute__((ext_vector_type(4)));

__device__ __forceinline__ void async_copy16(void* lds, const void* g) {
    __builtin_amdgcn_global_load_lds(
        (const __attribute__((address_space(1))) void*)g,
        (__attribute__((address_space(3))) void*)lds, 16, 0, 0);
}

// ---------------- CSR build ----------------

__global__ void count_kernel(const int* __restrict__ src, int* __restrict__ counts, int E) {
    int e = blockIdx.x * blockDim.x + threadIdx.x;
    if (e < E) atomicAdd(&counts[src[e]], 1);
}

__global__ __launch_bounds__(1024) void scan_kernel(const int4* __restrict__ counts4,
                                                    int* __restrict__ offsets,
                                                    int* __restrict__ cursor,
                                                    int n4, int n) {
    __shared__ int wsum[16];
    __shared__ int chunk_base;
    if (threadIdx.x == 0) chunk_base = 0;
    __syncthreads();
    const int lane = threadIdx.x & 63;
    const int wid  = threadIdx.x >> 6;
    const int iters = (n4 + 1023) / 1024;
    for (int it = 0; it < iters; ++it) {
        int i4 = it * 1024 + threadIdx.x;
        int4 c = make_int4(0, 0, 0, 0);
        if (i4 < n4) c = counts4[i4];
        int s = c.x + c.y + c.z + c.w;
        int x = s;
        #pragma unroll
        for (int d = 1; d < 64; d <<= 1) {
            int y = __shfl_up(x, d);
            if (lane >= d) x += y;
        }
        if (lane == 63) wsum[wid] = x;
        __syncthreads();
        if (threadIdx.x < 16) {
            int t = wsum[threadIdx.x];
            #pragma unroll
            for (int d = 1; d < 16; d <<= 1) {
                int y = __shfl_up(t, d);
                if (lane >= d) t += y;
            }
            wsum[threadIdx.x] = t;
        }
        __syncthreads();
        int excl = x - s + (wid ? wsum[wid - 1] : 0);
        int base = chunk_base;
        if (i4 < n4) {
            int4 o;
            o.x = base + excl;
            o.y = o.x + c.x;
            o.z = o.y + c.y;
            o.w = o.z + c.z;
            ((int4*)offsets)[i4] = o;
            ((int4*)cursor)[i4]  = o;
        }
        __syncthreads();
        if (threadIdx.x == 0) chunk_base += wsum[15];
        __syncthreads();
    }
    if (threadIdx.x == 0) offsets[n] = chunk_base;
}

__global__ void scatter_kernel(const int* __restrict__ src, const int* __restrict__ dst,
                               const float* __restrict__ val, int* __restrict__ cursor,
                               int2* __restrict__ pairs, int E) {
    int e = blockIdx.x * blockDim.x + threadIdx.x;
    if (e < E) {
        int s = src[e];
        int p = atomicAdd(&cursor[s], 1);
        pairs[p] = make_int2(dst[e], __float_as_int(val[e]));
    }
}

// ---------------- casts ----------------

__global__ void cast_f32_f16(const float* __restrict__ in, _Float16* __restrict__ out, int n4) {
    int stride = gridDim.x * blockDim.x;
    for (int j = blockIdx.x * blockDim.x + threadIdx.x; j < n4; j += stride) {
        float4 v = ((const float4*)in)[j];
        f16x4 o = { (_Float16)v.x, (_Float16)v.y, (_Float16)v.z, (_Float16)v.w };
        ((f16x4*)out)[j] = o;
    }
}

// out[n][k] = (f16) in[k][n]
__global__ void transpose_cast(const float* __restrict__ in, _Float16* __restrict__ out, int K, int N) {
    int idx = blockIdx.x * blockDim.x + threadIdx.x;
    if (idx < K * N) {
        int k = idx / N, n = idx % N;
        out[(size_t)n * K + k] = (_Float16)in[idx];
    }
}

// ---------------- fp16 MFMA GEMM: C[M,N] = A[M,K] @ Bt[N,K]^T ----------------
// BM=128, BK=32, 256 threads = 4 waves (2x2). Wave tile 64 x (BN/2).
// LDS rows of 64B with chunk-XOR swizzle (global-source pre-swizzle + swizzled read).

template<int BN, int NR>
__global__ __launch_bounds__(256) void gemm_f16(const _Float16* __restrict__ A,
                                                const _Float16* __restrict__ Bt,
                                                _Float16* __restrict__ C,
                                                int M, int N, int K) {
    __shared__ _Float16 As[128 * 32];
    __shared__ _Float16 Bs[BN * 32];
    const int tid  = threadIdx.x;
    const int lane = tid & 63;
    const int wave = tid >> 6;
    const int wm = wave >> 1, wn = wave & 1;
    const int m0 = blockIdx.x * 128;
    const int n0 = blockIdx.y * BN;

    f32x4 acc[4][NR];
    #pragma unroll
    for (int i = 0; i < 4; ++i)
        #pragma unroll
        for (int j = 0; j < NR; ++j) acc[i][j] = (f32x4){0.f, 0.f, 0.f, 0.f};

    for (int k0 = 0; k0 < K; k0 += 32) {
        // stage A: 128 rows x 32 k = 8192 B -> 2 issues; source pre-swizzled
        #pragma unroll
        for (int it = 0; it < 2; ++it) {
            int i = it * 256 + tid;      // 16B chunk index (4 per 64B row)
            int r = i >> 2;
            int q = (i & 3) ^ (r & 3);   // logical k-chunk stored at this physical slot
            int gr = m0 + r; if (gr >= M) gr = M - 1;
            async_copy16((char*)As + i * 16, A + (size_t)gr * K + k0 + q * 8);
        }
        // stage B: BN rows x 32 k -> BN/64 issues
        #pragma unroll
        for (int it = 0; it < BN / 64; ++it) {
            int i = it * 256 + tid;
            int r = i >> 2;
            int q = (i & 3) ^ (r & 3);
            async_copy16((char*)Bs + i * 16, Bt + (size_t)(n0 + r) * K + k0 + q * 8);
        }
        __syncthreads();

        f16x8 af[4], bf[NR];
        const int kc = lane >> 4;        // k-chunk 0..3 (8 elems each)
        #pragma unroll
        for (int m = 0; m < 4; ++m) {
            int r = wm * 64 + m * 16 + (lane & 15);
            af[m] = *(const f16x8*)((const char*)As + r * 64 + ((kc ^ (r & 3)) * 16));
        }
        #pragma unroll
        for (int n = 0; n < NR; ++n) {
            int r = wn * (BN / 2) + n * 16 + (lane & 15);
            bf[n] = *(const f16x8*)((const char*)Bs + r * 64 + ((kc ^ (r & 3)) * 16));
        }
        #pragma unroll
        for (int m = 0; m < 4; ++m)
            #pragma unroll
            for (int n = 0; n < NR; ++n)
                acc[m][n] = __builtin_amdgcn_mfma_f32_16x16x32_f16(af[m], bf[n], acc[m][n], 0, 0, 0);
        __syncthreads();
    }

    #pragma unroll
    for (int m = 0; m < 4; ++m)
        #pragma unroll
        for (int n = 0; n < NR; ++n)
            #pragma unroll
            for (int r = 0; r < 4; ++r) {
                int row = m0 + wm * 64 + m * 16 + (lane >> 4) * 4 + r;
                int col = n0 + wn * (BN / 2) + n * 16 + (lane & 15);
                if (row < M) C[(size_t)row * N + col] = (_Float16)acc[m][n][r];
            }
}

// ---------------- SpMM (fp16 gather, f32 accum) ----------------

__global__ __launch_bounds__(256) void spmm_relu_f16(const int* __restrict__ offs,
                                                     const int2* __restrict__ pairs,
                                                     const _Float16* __restrict__ dense,
                                                     _Float16* __restrict__ out, int n) {
    int node = blockIdx.x * 4 + (threadIdx.x >> 6);
    if (node >= n) return;
    int lane = threadIdx.x & 63;
    int beg = offs[node], end = offs[node + 1];
    float a0 = 0.f, a1 = 0.f, a2 = 0.f, a3 = 0.f;
    for (int k = beg; k < end; ++k) {
        int2 pr = pairs[k];
        float v = __int_as_float(pr.y);
        f16x4 p = *(const f16x4*)(dense + (size_t)pr.x * 256 + lane * 4);
        a0 = fmaf(v, (float)p[0], a0);
        a1 = fmaf(v, (float)p[1], a1);
        a2 = fmaf(v, (float)p[2], a2);
        a3 = fmaf(v, (float)p[3], a3);
    }
    f16x4 o = { (_Float16)fmaxf(a0, 0.f), (_Float16)fmaxf(a1, 0.f),
                (_Float16)fmaxf(a2, 0.f), (_Float16)fmaxf(a3, 0.f) };
    *(f16x4*)(out + (size_t)node * 256 + lane * 4) = o;
}

__global__ __launch_bounds__(256) void spmm64_f16(const int* __restrict__ offs,
                                                  const int2* __restrict__ pairs,
                                                  const _Float16* __restrict__ dense,
                                                  float* __restrict__ out, int n) {
    int node = blockIdx.x * 4 + (threadIdx.x >> 6);
    if (node >= n) return;
    int lane = threadIdx.x & 63;
    int beg = offs[node], end = offs[node + 1];
    float acc = 0.f;
    for (int k = beg; k < end; ++k) {
        int2 pr = pairs[k];
        acc = fmaf(__int_as_float(pr.y), (float)dense[(size_t)pr.x * 64 + lane], acc);
    }
    out[(size_t)node * 64 + lane] = acc;
}

// ---------------- launch ----------------

extern "C" void kernel_launch(void* const* d_in, const int* in_sizes, int n_in,
                              void* d_out, int out_size, void* d_ws, size_t ws_size,
                              hipStream_t stream) {
    const float* x    = (const float*)d_in[0];
    const int*   esrc = (const int*)d_in[1];
    const int*   edst = (const int*)d_in[2];
    const float* eval = (const float*)d_in[3];
    const float* w1   = (const float*)d_in[4];
    const float* w2   = (const float*)d_in[5];
    float* out = (float*)d_out;

    char* ws = (char*)d_ws;
    _Float16* xh     = (_Float16*)(ws + 0);            // 102,400,000 B
    _Float16* pre    = (_Float16*)(ws + 102400000);    // 51,200,000 B
    int2*     pairs  = (int2*)(ws + 153600000);        // 25,600,000 B
    int*      counts = (int*)(ws + 179200000);         // 400,000 B
    int*      offs   = (int*)(ws + 179600000);         // 400,004 B (padded)
    int*      cursor = (int*)(ws + 180000128);         // 400,000 B
    _Float16* w1t    = (_Float16*)(ws + 180400128);    // 262,144 B
    _Float16* w2t    = (_Float16*)(ws + 180662272);    // 32,768 B
    _Float16* h  = xh;                                 // xh dead after gemm1
    _Float16* h2 = pre;                                // pre dead after spmm1

    hipMemsetAsync(counts, 0, NN * sizeof(int), stream);
    count_kernel<<<(NE + 255) / 256, 256, 0, stream>>>(esrc, counts, NE);
    scan_kernel<<<1, 1024, 0, stream>>>((const int4*)counts, offs, cursor, NN / 4, NN);
    scatter_kernel<<<(NE + 255) / 256, 256, 0, stream>>>(esrc, edst, eval, cursor, pairs, NE);

    cast_f32_f16<<<2048, 256, 0, stream>>>(x, xh, NN * IN_DIM / 4);
    transpose_cast<<<(IN_DIM * HID + 255) / 256, 256, 0, stream>>>(w1, w1t, IN_DIM, HID);
    transpose_cast<<<(HID * OUTD + 255) / 256, 256, 0, stream>>>(w2, w2t, HID, OUTD);

    dim3 g1((NN + 127) / 128, HID / 128);
    gemm_f16<128, 4><<<g1, 256, 0, stream>>>(xh, w1t, pre, NN, HID, IN_DIM);

    spmm_relu_f16<<<(NN + 3) / 4, 256, 0, stream>>>(offs, pairs, pre, h, NN);

    dim3 g2((NN + 127) / 128, 1);
    gemm_f16<64, 2><<<g2, 256, 0, stream>>>(h, w2t, h2, NN, OUTD, HID);

    spmm64_f16<<<(NN + 3) / 4, 256, 0, stream>>>(offs, pairs, h2, out, NN);
}

// Round 3
// 830.004 us; speedup vs baseline: 1.7480x; 1.2807x over previous
//
#include <hip/hip_runtime.h>

#define NN 100000
#define NE 3200000
#define IN_DIM 512
#define HID 256
#define OUTD 64

typedef _Float16 f16x8 __attribute__((ext_vector_type(8)));
typedef _Float16 f16x4 __attribute__((ext_vector_type(4)));
typedef _Float16 f16x2 __attribute__((ext_vector_type(2)));
typedef float f32x4 __attribute__((ext_vector_type(4)));

__device__ __forceinline__ void async_copy16(void* lds, const void* g) {
    __builtin_amdgcn_global_load_lds(
        (const __attribute__((address_space(1))) void*)g,
        (__attribute__((address_space(3))) void*)lds, 16, 0, 0);
}

// ---------------- CSR build ----------------

__global__ void count_kernel(const int* __restrict__ src, int* __restrict__ counts, int E) {
    int e = blockIdx.x * blockDim.x + threadIdx.x;
    if (e < E) atomicAdd(&counts[src[e]], 1);
}

__global__ __launch_bounds__(1024) void scan_kernel(const int4* __restrict__ counts4,
                                                    int* __restrict__ offsets,
                                                    int* __restrict__ cursor,
                                                    int n4, int n) {
    __shared__ int wsum[16];
    __shared__ int chunk_base;
    if (threadIdx.x == 0) chunk_base = 0;
    __syncthreads();
    const int lane = threadIdx.x & 63;
    const int wid  = threadIdx.x >> 6;
    const int iters = (n4 + 1023) / 1024;
    for (int it = 0; it < iters; ++it) {
        int i4 = it * 1024 + threadIdx.x;
        int4 c = make_int4(0, 0, 0, 0);
        if (i4 < n4) c = counts4[i4];
        int s = c.x + c.y + c.z + c.w;
        int x = s;
        #pragma unroll
        for (int d = 1; d < 64; d <<= 1) {
            int y = __shfl_up(x, d);
            if (lane >= d) x += y;
        }
        if (lane == 63) wsum[wid] = x;
        __syncthreads();
        if (threadIdx.x < 16) {
            int t = wsum[threadIdx.x];
            #pragma unroll
            for (int d = 1; d < 16; d <<= 1) {
                int y = __shfl_up(t, d);
                if (lane >= d) t += y;
            }
            wsum[threadIdx.x] = t;
        }
        __syncthreads();
        int excl = x - s + (wid ? wsum[wid - 1] : 0);
        int base = chunk_base;
        if (i4 < n4) {
            int4 o;
            o.x = base + excl;
            o.y = o.x + c.x;
            o.z = o.y + c.y;
            o.w = o.z + c.z;
            ((int4*)offsets)[i4] = o;
            ((int4*)cursor)[i4]  = o;
        }
        __syncthreads();
        if (threadIdx.x == 0) chunk_base += wsum[15];
        __syncthreads();
    }
    if (threadIdx.x == 0) offsets[n] = chunk_base;
}

__global__ void scatter_kernel(const int* __restrict__ src, const int* __restrict__ dst,
                               const float* __restrict__ val, int* __restrict__ cursor,
                               int2* __restrict__ pairs, int E) {
    int e = blockIdx.x * blockDim.x + threadIdx.x;
    if (e < E) {
        int s = src[e];
        int p = atomicAdd(&cursor[s], 1);
        pairs[p] = make_int2(dst[e], __float_as_int(val[e]));
    }
}

// ---------------- casts ----------------

__global__ void cast_f32_f16(const float* __restrict__ in, _Float16* __restrict__ out, int n4) {
    int stride = gridDim.x * blockDim.x;
    for (int j = blockIdx.x * blockDim.x + threadIdx.x; j < n4; j += stride) {
        float4 v = ((const float4*)in)[j];
        f16x4 o = { (_Float16)v.x, (_Float16)v.y, (_Float16)v.z, (_Float16)v.w };
        ((f16x4*)out)[j] = o;
    }
}

// out[n][k] = (f16) in[k][n]
__global__ void transpose_cast(const float* __restrict__ in, _Float16* __restrict__ out, int K, int N) {
    int idx = blockIdx.x * blockDim.x + threadIdx.x;
    if (idx < K * N) {
        int k = idx / N, n = idx % N;
        out[(size_t)n * K + k] = (_Float16)in[idx];
    }
}

// ---------------- fp16 MFMA GEMM: C[M,N] = A[M,K] @ Bt[N,K]^T ----------------
// BM=128, BK=32, 256 threads = 4 waves (2x2). Wave tile 64 x (BN/2).
// LDS rows of 64B with chunk-XOR swizzle (global-source pre-swizzle + swizzled read).

template<int BN, int NR>
__global__ __launch_bounds__(256) void gemm_f16(const _Float16* __restrict__ A,
                                                const _Float16* __restrict__ Bt,
                                                _Float16* __restrict__ C,
                                                int M, int N, int K) {
    __shared__ _Float16 As[128 * 32];
    __shared__ _Float16 Bs[BN * 32];
    const int tid  = threadIdx.x;
    const int lane = tid & 63;
    const int wave = tid >> 6;
    const int wm = wave >> 1, wn = wave & 1;
    const int m0 = blockIdx.x * 128;
    const int n0 = blockIdx.y * BN;

    f32x4 acc[4][NR];
    #pragma unroll
    for (int i = 0; i < 4; ++i)
        #pragma unroll
        for (int j = 0; j < NR; ++j) acc[i][j] = (f32x4){0.f, 0.f, 0.f, 0.f};

    for (int k0 = 0; k0 < K; k0 += 32) {
        // stage A: 128 rows x 32 k = 8192 B -> 2 issues; source pre-swizzled
        #pragma unroll
        for (int it = 0; it < 2; ++it) {
            int i = it * 256 + tid;      // 16B chunk index (4 per 64B row)
            int r = i >> 2;
            int q = (i & 3) ^ (r & 3);   // logical k-chunk stored at this physical slot
            int gr = m0 + r; if (gr >= M) gr = M - 1;
            async_copy16((char*)As + i * 16, A + (size_t)gr * K + k0 + q * 8);
        }
        // stage B: BN rows x 32 k -> BN/64 issues
        #pragma unroll
        for (int it = 0; it < BN / 64; ++it) {
            int i = it * 256 + tid;
            int r = i >> 2;
            int q = (i & 3) ^ (r & 3);
            async_copy16((char*)Bs + i * 16, Bt + (size_t)(n0 + r) * K + k0 + q * 8);
        }
        __syncthreads();

        f16x8 af[4], bf[NR];
        const int kc = lane >> 4;        // k-chunk 0..3 (8 elems each)
        #pragma unroll
        for (int m = 0; m < 4; ++m) {
            int r = wm * 64 + m * 16 + (lane & 15);
            af[m] = *(const f16x8*)((const char*)As + r * 64 + ((kc ^ (r & 3)) * 16));
        }
        #pragma unroll
        for (int n = 0; n < NR; ++n) {
            int r = wn * (BN / 2) + n * 16 + (lane & 15);
            bf[n] = *(const f16x8*)((const char*)Bs + r * 64 + ((kc ^ (r & 3)) * 16));
        }
        #pragma unroll
        for (int m = 0; m < 4; ++m)
            #pragma unroll
            for (int n = 0; n < NR; ++n)
                acc[m][n] = __builtin_amdgcn_mfma_f32_16x16x32_f16(af[m], bf[n], acc[m][n], 0, 0, 0);
        __syncthreads();
    }

    #pragma unroll
    for (int m = 0; m < 4; ++m)
        #pragma unroll
        for (int n = 0; n < NR; ++n)
            #pragma unroll
            for (int r = 0; r < 4; ++r) {
                int row = m0 + wm * 64 + m * 16 + (lane >> 4) * 4 + r;
                int col = n0 + wn * (BN / 2) + n * 16 + (lane & 15);
                if (row < M) C[(size_t)row * N + col] = (_Float16)acc[m][n][r];
            }
}

// ---------------- SpMM (fp16 gather, f32 accum), software-pipelined ----------------

__global__ __launch_bounds__(256) void spmm_relu_f16(const int* __restrict__ offs,
                                                     const int2* __restrict__ pairs,
                                                     const _Float16* __restrict__ dense,
                                                     _Float16* __restrict__ out, int n) {
    int node = blockIdx.x * 4 + (threadIdx.x >> 6);
    if (node >= n) return;
    int lane = threadIdx.x & 63;
    int beg = offs[node], end = offs[node + 1];
    const _Float16* dbase = dense + lane * 4;
    float a0 = 0.f, a1 = 0.f, a2 = 0.f, a3 = 0.f;
    int k = beg;
    for (; k + 8 <= end; k += 8) {
        int2 pr[8];
        #pragma unroll
        for (int j = 0; j < 8; ++j) pr[j] = pairs[k + j];
        f16x4 p[8];
        #pragma unroll
        for (int j = 0; j < 8; ++j)
            p[j] = *(const f16x4*)(dbase + (size_t)pr[j].x * 256);
        #pragma unroll
        for (int j = 0; j < 8; ++j) {
            float v = __int_as_float(pr[j].y);
            a0 = fmaf(v, (float)p[j][0], a0);
            a1 = fmaf(v, (float)p[j][1], a1);
            a2 = fmaf(v, (float)p[j][2], a2);
            a3 = fmaf(v, (float)p[j][3], a3);
        }
    }
    for (; k < end; ++k) {
        int2 pr = pairs[k];
        float v = __int_as_float(pr.y);
        f16x4 p = *(const f16x4*)(dbase + (size_t)pr.x * 256);
        a0 = fmaf(v, (float)p[0], a0);
        a1 = fmaf(v, (float)p[1], a1);
        a2 = fmaf(v, (float)p[2], a2);
        a3 = fmaf(v, (float)p[3], a3);
    }
    f16x4 o = { (_Float16)fmaxf(a0, 0.f), (_Float16)fmaxf(a1, 0.f),
                (_Float16)fmaxf(a2, 0.f), (_Float16)fmaxf(a3, 0.f) };
    *(f16x4*)(out + (size_t)node * 256 + lane * 4) = o;
}

// D=64: wave split into 2 edge-parity halves; lane covers 2 features (4B loads).
// Final f32 output.
__global__ __launch_bounds__(256) void spmm64_f16(const int* __restrict__ offs,
                                                  const int2* __restrict__ pairs,
                                                  const _Float16* __restrict__ dense,
                                                  float* __restrict__ out, int n) {
    int node = blockIdx.x * 4 + (threadIdx.x >> 6);
    if (node >= n) return;
    int lane = threadIdx.x & 63;
    int par = lane >> 5;         // which edge of the pair
    int fl  = lane & 31;         // feature-pair index: features 2*fl, 2*fl+1
    int beg = offs[node], end = offs[node + 1];
    const _Float16* dbase = dense + fl * 2;
    float a0 = 0.f, a1 = 0.f;
    int k = beg;
    for (; k + 16 <= end; k += 16) {
        int2 pr[8];
        #pragma unroll
        for (int j = 0; j < 8; ++j) pr[j] = pairs[k + 2 * j + par];
        f16x2 p[8];
        #pragma unroll
        for (int j = 0; j < 8; ++j)
            p[j] = *(const f16x2*)(dbase + (size_t)pr[j].x * 64);
        #pragma unroll
        for (int j = 0; j < 8; ++j) {
            float v = __int_as_float(pr[j].y);
            a0 = fmaf(v, (float)p[j][0], a0);
            a1 = fmaf(v, (float)p[j][1], a1);
        }
    }
    for (; k < end; k += 2) {
        int e = k + par;
        if (e < end) {
            int2 pr = pairs[e];
            float v = __int_as_float(pr.y);
            f16x2 p = *(const f16x2*)(dbase + (size_t)pr.x * 64);
            a0 = fmaf(v, (float)p[0], a0);
            a1 = fmaf(v, (float)p[1], a1);
        }
    }
    a0 += __shfl_xor(a0, 32);
    a1 += __shfl_xor(a1, 32);
    if (par == 0) {
        float2 o = make_float2(a0, a1);
        *(float2*)(out + (size_t)node * 64 + fl * 2) = o;
    }
}

// ---------------- launch ----------------

extern "C" void kernel_launch(void* const* d_in, const int* in_sizes, int n_in,
                              void* d_out, int out_size, void* d_ws, size_t ws_size,
                              hipStream_t stream) {
    const float* x    = (const float*)d_in[0];
    const int*   esrc = (const int*)d_in[1];
    const int*   edst = (const int*)d_in[2];
    const float* eval = (const float*)d_in[3];
    const float* w1   = (const float*)d_in[4];
    const float* w2   = (const float*)d_in[5];
    float* out = (float*)d_out;

    char* ws = (char*)d_ws;
    _Float16* xh     = (_Float16*)(ws + 0);            // 102,400,000 B
    _Float16* pre    = (_Float16*)(ws + 102400000);    // 51,200,000 B
    int2*     pairs  = (int2*)(ws + 153600000);        // 25,600,000 B
    int*      counts = (int*)(ws + 179200000);         // 400,000 B
    int*      offs   = (int*)(ws + 179600000);         // 400,004 B (padded)
    int*      cursor = (int*)(ws + 180000128);         // 400,000 B
    _Float16* w1t    = (_Float16*)(ws + 180400128);    // 262,144 B
    _Float16* w2t    = (_Float16*)(ws + 180662272);    // 32,768 B
    _Float16* h  = xh;                                 // xh dead after gemm1
    _Float16* h2 = pre;                                // pre dead after spmm1

    hipMemsetAsync(counts, 0, NN * sizeof(int), stream);
    count_kernel<<<(NE + 255) / 256, 256, 0, stream>>>(esrc, counts, NE);
    scan_kernel<<<1, 1024, 0, stream>>>((const int4*)counts, offs, cursor, NN / 4, NN);
    scatter_kernel<<<(NE + 255) / 256, 256, 0, stream>>>(esrc, edst, eval, cursor, pairs, NE);

    cast_f32_f16<<<2048, 256, 0, stream>>>(x, xh, NN * IN_DIM / 4);
    transpose_cast<<<(IN_DIM * HID + 255) / 256, 256, 0, stream>>>(w1, w1t, IN_DIM, HID);
    transpose_cast<<<(HID * OUTD + 255) / 256, 256, 0, stream>>>(w2, w2t, HID, OUTD);

    dim3 g1((NN + 127) / 128, HID / 128);
    gemm_f16<128, 4><<<g1, 256, 0, stream>>>(xh, w1t, pre, NN, HID, IN_DIM);

    spmm_relu_f16<<<(NN + 3) / 4, 256, 0, stream>>>(offs, pairs, pre, h, NN);

    dim3 g2((NN + 127) / 128, 1);
    gemm_f16<64, 2><<<g2, 256, 0, stream>>>(h, w2t, h2, NN, OUTD, HID);

    spmm64_f16<<<(NN + 3) / 4, 256, 0, stream>>>(offs, pairs, h2, out, NN);
}

// Round 4
// 728.274 us; speedup vs baseline: 1.9922x; 1.1397x over previous
//
#include <hip/hip_runtime.h>

#define NN 100000
#define NE 3200000
#define IN_DIM 512
#define HID 256
#define OUTD 64
#define NB 196            // ceil(100000/512) coarse buckets of 512 srcs

typedef _Float16 f16x8 __attribute__((ext_vector_type(8)));
typedef _Float16 f16x4 __attribute__((ext_vector_type(4)));
typedef _Float16 f16x2 __attribute__((ext_vector_type(2)));
typedef float f32x4 __attribute__((ext_vector_type(4)));

__device__ __forceinline__ void async_copy16(void* lds, const void* g) {
    __builtin_amdgcn_global_load_lds(
        (const __attribute__((address_space(1))) void*)g,
        (__attribute__((address_space(3))) void*)lds, 16, 0, 0);
}

// ---------------- CSR build ----------------

__global__ void count_kernel(const int* __restrict__ src, int* __restrict__ counts, int E) {
    int e = blockIdx.x * blockDim.x + threadIdx.x;
    if (e < E) atomicAdd(&counts[src[e]], 1);
}

__global__ __launch_bounds__(1024) void scan_kernel(const int4* __restrict__ counts4,
                                                    int* __restrict__ offsets,
                                                    int n4, int n) {
    __shared__ int wsum[16];
    __shared__ int chunk_base;
    if (threadIdx.x == 0) chunk_base = 0;
    __syncthreads();
    const int lane = threadIdx.x & 63;
    const int wid  = threadIdx.x >> 6;
    const int iters = (n4 + 1023) / 1024;
    for (int it = 0; it < iters; ++it) {
        int i4 = it * 1024 + threadIdx.x;
        int4 c = make_int4(0, 0, 0, 0);
        if (i4 < n4) c = counts4[i4];
        int s = c.x + c.y + c.z + c.w;
        int x = s;
        #pragma unroll
        for (int d = 1; d < 64; d <<= 1) {
            int y = __shfl_up(x, d);
            if (lane >= d) x += y;
        }
        if (lane == 63) wsum[wid] = x;
        __syncthreads();
        if (threadIdx.x < 16) {
            int t = wsum[threadIdx.x];
            #pragma unroll
            for (int d = 1; d < 16; d <<= 1) {
                int y = __shfl_up(t, d);
                if (lane >= d) t += y;
            }
            wsum[threadIdx.x] = t;
        }
        __syncthreads();
        int excl = x - s + (wid ? wsum[wid - 1] : 0);
        int base = chunk_base;
        if (i4 < n4) {
            int4 o;
            o.x = base + excl;
            o.y = o.x + c.x;
            o.z = o.y + c.y;
            o.w = o.z + c.z;
            ((int4*)offsets)[i4] = o;
        }
        __syncthreads();
        if (threadIdx.x == 0) chunk_base += wsum[15];
        __syncthreads();
    }
    if (threadIdx.x == 0) offsets[n] = chunk_base;
}

__global__ void init_bc_kernel(const int* __restrict__ offsets, int* __restrict__ bc) {
    int t = threadIdx.x;
    if (t < NB) bc[t] = offsets[t * 512];
}

// bin pass: bucket-sort edges to 512-src granularity with dense, block-contiguous writes
__global__ __launch_bounds__(256) void bin_kernel(const int* __restrict__ src,
                                                  const int* __restrict__ dst,
                                                  const float* __restrict__ val,
                                                  int* __restrict__ bucket_cursor,
                                                  int* __restrict__ srcs_tmp,
                                                  int2* __restrict__ pairs_tmp,
                                                  int E, int epb) {
    __shared__ int hist[NB];
    __shared__ int base[NB];
    const int t = threadIdx.x;
    for (int i = t; i < NB; i += 256) hist[i] = 0;
    __syncthreads();
    const int lo = blockIdx.x * epb;
    const int hi = min(E, lo + epb);
    for (int e = lo + t; e < hi; e += 256)
        atomicAdd(&hist[src[e] >> 9], 1);
    __syncthreads();
    for (int i = t; i < NB; i += 256) {
        base[i] = atomicAdd(&bucket_cursor[i], hist[i]);
        hist[i] = 0;
    }
    __syncthreads();
    for (int e = lo + t; e < hi; e += 256) {
        int s = src[e];
        int b = s >> 9;
        int l = atomicAdd(&hist[b], 1);
        int pos = base[b] + l;
        srcs_tmp[pos] = s;
        pairs_tmp[pos] = make_int2(dst[e], __float_as_int(val[e]));
    }
}

// finalize: one block per bucket; LDS per-src cursors; all writes in one 131KB window
__global__ __launch_bounds__(1024) void csr_kernel(const int* __restrict__ offs,
                                                   const int* __restrict__ srcs_tmp,
                                                   const int2* __restrict__ pairs_tmp,
                                                   int2* __restrict__ pairs, int n) {
    __shared__ int cur[512];
    const int s0 = blockIdx.x * 512;
    const int t = threadIdx.x;
    if (t < 512) {
        int s = s0 + t;
        cur[t] = (s < n) ? offs[s] : 0;
    }
    __syncthreads();
    const int lo = offs[s0];
    const int hi = offs[min(s0 + 512, n)];
    for (int i = lo + t; i < hi; i += 1024) {
        int s = srcs_tmp[i];
        int p = atomicAdd(&cur[s - s0], 1);
        pairs[p] = pairs_tmp[i];
    }
}

// ---------------- casts ----------------

__global__ void cast_f32_f16(const float* __restrict__ in, _Float16* __restrict__ out, int n4) {
    int stride = gridDim.x * blockDim.x;
    for (int j = blockIdx.x * blockDim.x + threadIdx.x; j < n4; j += stride) {
        float4 v = ((const float4*)in)[j];
        f16x4 o = { (_Float16)v.x, (_Float16)v.y, (_Float16)v.z, (_Float16)v.w };
        ((f16x4*)out)[j] = o;
    }
}

// out[n][k] = (f16) in[k][n]
__global__ void transpose_cast(const float* __restrict__ in, _Float16* __restrict__ out, int K, int N) {
    int idx = blockIdx.x * blockDim.x + threadIdx.x;
    if (idx < K * N) {
        int k = idx / N, n = idx % N;
        out[(size_t)n * K + k] = (_Float16)in[idx];
    }
}

// ---------------- fp16 MFMA GEMM: C[M,N] = A[M,K] @ Bt[N,K]^T ----------------

template<int BN, int NR>
__global__ __launch_bounds__(256) void gemm_f16(const _Float16* __restrict__ A,
                                                const _Float16* __restrict__ Bt,
                                                _Float16* __restrict__ C,
                                                int M, int N, int K) {
    __shared__ _Float16 As[128 * 32];
    __shared__ _Float16 Bs[BN * 32];
    const int tid  = threadIdx.x;
    const int lane = tid & 63;
    const int wave = tid >> 6;
    const int wm = wave >> 1, wn = wave & 1;
    const int m0 = blockIdx.x * 128;
    const int n0 = blockIdx.y * BN;

    f32x4 acc[4][NR];
    #pragma unroll
    for (int i = 0; i < 4; ++i)
        #pragma unroll
        for (int j = 0; j < NR; ++j) acc[i][j] = (f32x4){0.f, 0.f, 0.f, 0.f};

    for (int k0 = 0; k0 < K; k0 += 32) {
        #pragma unroll
        for (int it = 0; it < 2; ++it) {
            int i = it * 256 + tid;
            int r = i >> 2;
            int q = (i & 3) ^ (r & 3);
            int gr = m0 + r; if (gr >= M) gr = M - 1;
            async_copy16((char*)As + i * 16, A + (size_t)gr * K + k0 + q * 8);
        }
        #pragma unroll
        for (int it = 0; it < BN / 64; ++it) {
            int i = it * 256 + tid;
            int r = i >> 2;
            int q = (i & 3) ^ (r & 3);
            async_copy16((char*)Bs + i * 16, Bt + (size_t)(n0 + r) * K + k0 + q * 8);
        }
        __syncthreads();

        f16x8 af[4], bf[NR];
        const int kc = lane >> 4;
        #pragma unroll
        for (int m = 0; m < 4; ++m) {
            int r = wm * 64 + m * 16 + (lane & 15);
            af[m] = *(const f16x8*)((const char*)As + r * 64 + ((kc ^ (r & 3)) * 16));
        }
        #pragma unroll
        for (int n = 0; n < NR; ++n) {
            int r = wn * (BN / 2) + n * 16 + (lane & 15);
            bf[n] = *(const f16x8*)((const char*)Bs + r * 64 + ((kc ^ (r & 3)) * 16));
        }
        #pragma unroll
        for (int m = 0; m < 4; ++m)
            #pragma unroll
            for (int n = 0; n < NR; ++n)
                acc[m][n] = __builtin_amdgcn_mfma_f32_16x16x32_f16(af[m], bf[n], acc[m][n], 0, 0, 0);
        __syncthreads();
    }

    #pragma unroll
    for (int m = 0; m < 4; ++m)
        #pragma unroll
        for (int n = 0; n < NR; ++n)
            #pragma unroll
            for (int r = 0; r < 4; ++r) {
                int row = m0 + wm * 64 + m * 16 + (lane >> 4) * 4 + r;
                int col = n0 + wn * (BN / 2) + n * 16 + (lane & 15);
                if (row < M) C[(size_t)row * N + col] = (_Float16)acc[m][n][r];
            }
}

// ---------------- SpMM (fp16 gather, f32 accum), software-pipelined ----------------

__global__ __launch_bounds__(256) void spmm_relu_f16(const int* __restrict__ offs,
                                                     const int2* __restrict__ pairs,
                                                     const _Float16* __restrict__ dense,
                                                     _Float16* __restrict__ out, int n) {
    int node = blockIdx.x * 4 + (threadIdx.x >> 6);
    if (node >= n) return;
    int lane = threadIdx.x & 63;
    int beg = offs[node], end = offs[node + 1];
    const _Float16* dbase = dense + lane * 4;
    float a0 = 0.f, a1 = 0.f, a2 = 0.f, a3 = 0.f;
    int k = beg;
    for (; k + 8 <= end; k += 8) {
        int2 pr[8];
        #pragma unroll
        for (int j = 0; j < 8; ++j) pr[j] = pairs[k + j];
        f16x4 p[8];
        #pragma unroll
        for (int j = 0; j < 8; ++j)
            p[j] = *(const f16x4*)(dbase + (size_t)pr[j].x * 256);
        #pragma unroll
        for (int j = 0; j < 8; ++j) {
            float v = __int_as_float(pr[j].y);
            a0 = fmaf(v, (float)p[j][0], a0);
            a1 = fmaf(v, (float)p[j][1], a1);
            a2 = fmaf(v, (float)p[j][2], a2);
            a3 = fmaf(v, (float)p[j][3], a3);
        }
    }
    for (; k < end; ++k) {
        int2 pr = pairs[k];
        float v = __int_as_float(pr.y);
        f16x4 p = *(const f16x4*)(dbase + (size_t)pr.x * 256);
        a0 = fmaf(v, (float)p[0], a0);
        a1 = fmaf(v, (float)p[1], a1);
        a2 = fmaf(v, (float)p[2], a2);
        a3 = fmaf(v, (float)p[3], a3);
    }
    f16x4 o = { (_Float16)fmaxf(a0, 0.f), (_Float16)fmaxf(a1, 0.f),
                (_Float16)fmaxf(a2, 0.f), (_Float16)fmaxf(a3, 0.f) };
    *(f16x4*)(out + (size_t)node * 256 + lane * 4) = o;
}

__global__ __launch_bounds__(256) void spmm64_f16(const int* __restrict__ offs,
                                                  const int2* __restrict__ pairs,
                                                  const _Float16* __restrict__ dense,
                                                  float* __restrict__ out, int n) {
    int node = blockIdx.x * 4 + (threadIdx.x >> 6);
    if (node >= n) return;
    int lane = threadIdx.x & 63;
    int par = lane >> 5;
    int fl  = lane & 31;
    int beg = offs[node], end = offs[node + 1];
    const _Float16* dbase = dense + fl * 2;
    float a0 = 0.f, a1 = 0.f;
    int k = beg;
    for (; k + 16 <= end; k += 16) {
        int2 pr[8];
        #pragma unroll
        for (int j = 0; j < 8; ++j) pr[j] = pairs[k + 2 * j + par];
        f16x2 p[8];
        #pragma unroll
        for (int j = 0; j < 8; ++j)
            p[j] = *(const f16x2*)(dbase + (size_t)pr[j].x * 64);
        #pragma unroll
        for (int j = 0; j < 8; ++j) {
            float v = __int_as_float(pr[j].y);
            a0 = fmaf(v, (float)p[j][0], a0);
            a1 = fmaf(v, (float)p[j][1], a1);
        }
    }
    for (; k < end; k += 2) {
        int e = k + par;
        if (e < end) {
            int2 pr = pairs[e];
            float v = __int_as_float(pr.y);
            f16x2 p = *(const f16x2*)(dbase + (size_t)pr.x * 64);
            a0 = fmaf(v, (float)p[0], a0);
            a1 = fmaf(v, (float)p[1], a1);
        }
    }
    a0 += __shfl_xor(a0, 32);
    a1 += __shfl_xor(a1, 32);
    if (par == 0) {
        float2 o = make_float2(a0, a1);
        *(float2*)(out + (size_t)node * 64 + fl * 2) = o;
    }
}

// ---------------- launch ----------------

extern "C" void kernel_launch(void* const* d_in, const int* in_sizes, int n_in,
                              void* d_out, int out_size, void* d_ws, size_t ws_size,
                              hipStream_t stream) {
    const float* x    = (const float*)d_in[0];
    const int*   esrc = (const int*)d_in[1];
    const int*   edst = (const int*)d_in[2];
    const float* eval = (const float*)d_in[3];
    const float* w1   = (const float*)d_in[4];
    const float* w2   = (const float*)d_in[5];
    float* out = (float*)d_out;

    char* ws = (char*)d_ws;
    _Float16* xh      = (_Float16*)(ws + 0);            // 102,400,000 B
    _Float16* pre     = (_Float16*)(ws + 102400000);    //  51,200,000 B
    int2*     pairs   = (int2*)(ws + 153600000);        //  25,600,000 B
    int2*     pairs_t = (int2*)(ws + 179200000);        //  25,600,000 B
    int*      srcs_t  = (int*)(ws + 204800000);         //  12,800,000 B
    int*      counts  = (int*)(ws + 217600000);         //     400,000 B
    int*      offs    = (int*)(ws + 218000000);         //     400,128 B (100001 ints, padded)
    int*      bc      = (int*)(ws + 218400128);         //       1,024 B
    _Float16* w1t     = (_Float16*)(ws + 218401152);    //     262,144 B
    _Float16* w2t     = (_Float16*)(ws + 218663296);    //      32,768 B
    _Float16* h  = xh;                                  // xh dead after gemm1
    _Float16* h2 = pre;                                 // pre dead after spmm1

    hipMemsetAsync(counts, 0, NN * sizeof(int), stream);
    count_kernel<<<(NE + 255) / 256, 256, 0, stream>>>(esrc, counts, NE);
    scan_kernel<<<1, 1024, 0, stream>>>((const int4*)counts, offs, NN / 4, NN);
    init_bc_kernel<<<1, 256, 0, stream>>>(offs, bc);
    const int nblk = 1024, epb = (NE + nblk - 1) / nblk;   // 3125
    bin_kernel<<<nblk, 256, 0, stream>>>(esrc, edst, eval, bc, srcs_t, pairs_t, NE, epb);
    csr_kernel<<<NB, 1024, 0, stream>>>(offs, srcs_t, pairs_t, pairs, NN);

    cast_f32_f16<<<2048, 256, 0, stream>>>(x, xh, NN * IN_DIM / 4);
    transpose_cast<<<(IN_DIM * HID + 255) / 256, 256, 0, stream>>>(w1, w1t, IN_DIM, HID);
    transpose_cast<<<(HID * OUTD + 255) / 256, 256, 0, stream>>>(w2, w2t, HID, OUTD);

    dim3 g1((NN + 127) / 128, HID / 128);
    gemm_f16<128, 4><<<g1, 256, 0, stream>>>(xh, w1t, pre, NN, HID, IN_DIM);

    spmm_relu_f16<<<(NN + 3) / 4, 256, 0, stream>>>(offs, pairs, pre, h, NN);

    dim3 g2((NN + 127) / 128, 1);
    gemm_f16<64, 2><<<g2, 256, 0, stream>>>(h, w2t, h2, NN, OUTD, HID);

    spmm64_f16<<<(NN + 3) / 4, 256, 0, stream>>>(offs, pairs, h2, out, NN);
}

// Round 5
// 707.285 us; speedup vs baseline: 2.0513x; 1.0297x over previous
//
#include <hip/hip_runtime.h>

#define NN 100000
#define NE 3200000
#define IN_DIM 512
#define HID 256
#define OUTD 64
#define NB 196            // ceil(100000/512) coarse buckets of 512 srcs

typedef _Float16 f16x8 __attribute__((ext_vector_type(8)));
typedef _Float16 f16x4 __attribute__((ext_vector_type(4)));
typedef _Float16 f16x2 __attribute__((ext_vector_type(2)));
typedef float f32x4 __attribute__((ext_vector_type(4)));

__device__ __forceinline__ void async_copy16(void* lds, const void* g) {
    __builtin_amdgcn_global_load_lds(
        (const __attribute__((address_space(1))) void*)g,
        (__attribute__((address_space(3))) void*)lds, 16, 0, 0);
}

// ---------------- CSR build ----------------

__global__ void count_kernel(const int* __restrict__ src, int* __restrict__ counts, int E) {
    int e = blockIdx.x * blockDim.x + threadIdx.x;
    if (e < E) atomicAdd(&counts[src[e]], 1);
}

__global__ __launch_bounds__(1024) void scan_kernel(const int4* __restrict__ counts4,
                                                    int* __restrict__ offsets,
                                                    int n4, int n) {
    __shared__ int wsum[16];
    __shared__ int chunk_base;
    if (threadIdx.x == 0) chunk_base = 0;
    __syncthreads();
    const int lane = threadIdx.x & 63;
    const int wid  = threadIdx.x >> 6;
    const int iters = (n4 + 1023) / 1024;
    for (int it = 0; it < iters; ++it) {
        int i4 = it * 1024 + threadIdx.x;
        int4 c = make_int4(0, 0, 0, 0);
        if (i4 < n4) c = counts4[i4];
        int s = c.x + c.y + c.z + c.w;
        int x = s;
        #pragma unroll
        for (int d = 1; d < 64; d <<= 1) {
            int y = __shfl_up(x, d);
            if (lane >= d) x += y;
        }
        if (lane == 63) wsum[wid] = x;
        __syncthreads();
        if (threadIdx.x < 16) {
            int t = wsum[threadIdx.x];
            #pragma unroll
            for (int d = 1; d < 16; d <<= 1) {
                int y = __shfl_up(t, d);
                if (lane >= d) t += y;
            }
            wsum[threadIdx.x] = t;
        }
        __syncthreads();
        int excl = x - s + (wid ? wsum[wid - 1] : 0);
        int base = chunk_base;
        if (i4 < n4) {
            int4 o;
            o.x = base + excl;
            o.y = o.x + c.x;
            o.z = o.y + c.y;
            o.w = o.z + c.z;
            ((int4*)offsets)[i4] = o;
        }
        __syncthreads();
        if (threadIdx.x == 0) chunk_base += wsum[15];
        __syncthreads();
    }
    if (threadIdx.x == 0) offsets[n] = chunk_base;
}

__global__ void init_bc_kernel(const int* __restrict__ offsets, int* __restrict__ bc) {
    int t = threadIdx.x;
    if (t < NB) bc[t] = offsets[t * 512];
}

__global__ __launch_bounds__(256) void bin_kernel(const int* __restrict__ src,
                                                  const int* __restrict__ dst,
                                                  const float* __restrict__ val,
                                                  int* __restrict__ bucket_cursor,
                                                  int* __restrict__ srcs_tmp,
                                                  int2* __restrict__ pairs_tmp,
                                                  int E, int epb) {
    __shared__ int hist[NB];
    __shared__ int base[NB];
    const int t = threadIdx.x;
    for (int i = t; i < NB; i += 256) hist[i] = 0;
    __syncthreads();
    const int lo = blockIdx.x * epb;
    const int hi = min(E, lo + epb);
    for (int e = lo + t; e < hi; e += 256)
        atomicAdd(&hist[src[e] >> 9], 1);
    __syncthreads();
    for (int i = t; i < NB; i += 256) {
        base[i] = atomicAdd(&bucket_cursor[i], hist[i]);
        hist[i] = 0;
    }
    __syncthreads();
    for (int e = lo + t; e < hi; e += 256) {
        int s = src[e];
        int b = s >> 9;
        int l = atomicAdd(&hist[b], 1);
        int pos = base[b] + l;
        srcs_tmp[pos] = s;
        pairs_tmp[pos] = make_int2(dst[e], __float_as_int(val[e]));
    }
}

__global__ __launch_bounds__(1024) void csr_kernel(const int* __restrict__ offs,
                                                   const int* __restrict__ srcs_tmp,
                                                   const int2* __restrict__ pairs_tmp,
                                                   int2* __restrict__ pairs, int n) {
    __shared__ int cur[512];
    const int s0 = blockIdx.x * 512;
    const int t = threadIdx.x;
    if (t < 512) {
        int s = s0 + t;
        cur[t] = (s < n) ? offs[s] : 0;
    }
    __syncthreads();
    const int lo = offs[s0];
    const int hi = offs[min(s0 + 512, n)];
    for (int i = lo + t; i < hi; i += 1024) {
        int s = srcs_tmp[i];
        int p = atomicAdd(&cur[s - s0], 1);
        pairs[p] = pairs_tmp[i];
    }
}

// ---------------- weight transpose-cast ----------------

// out[n][k] = (f16) in[k][n]
__global__ void transpose_cast(const float* __restrict__ in, _Float16* __restrict__ out, int K, int N) {
    int idx = blockIdx.x * blockDim.x + threadIdx.x;
    if (idx < K * N) {
        int k = idx / N, n = idx % N;
        out[(size_t)n * K + k] = (_Float16)in[idx];
    }
}

// ---------------- GEMM1: pre[M,256] = x[M,512](f32) @ w1t[256,512]^T ----------------
// BM=128, BN=256 (full N in one pass; x read exactly once), BK=32, 4 waves (2x2).
// A staged as f32 (128B rows, 8x16B chunks, XOR swizzle), converted to f16 at frag read.

__global__ __launch_bounds__(256) void gemm1_f32a(const float* __restrict__ A,
                                                  const _Float16* __restrict__ Bt,
                                                  _Float16* __restrict__ C,
                                                  int M) {
    __shared__ float    As[128 * 32];    // 16 KB
    __shared__ _Float16 Bs[256 * 32];    // 16 KB
    const int tid  = threadIdx.x;
    const int lane = tid & 63;
    const int wave = tid >> 6;
    const int wm = wave >> 1, wn = wave & 1;
    const int m0 = blockIdx.x * 128;

    f32x4 acc[4][8];
    #pragma unroll
    for (int i = 0; i < 4; ++i)
        #pragma unroll
        for (int j = 0; j < 8; ++j) acc[i][j] = (f32x4){0.f, 0.f, 0.f, 0.f};

    for (int k0 = 0; k0 < IN_DIM; k0 += 32) {
        // stage A: 128 rows x 32 f32 = 16 KB -> 1024 chunks, 4 issues
        #pragma unroll
        for (int it = 0; it < 4; ++it) {
            int i = it * 256 + tid;
            int r = i >> 3;              // row
            int cp = i & 7;              // physical 16B chunk in row
            int cl = cp ^ (r & 7);       // logical chunk (4 floats)
            int gr = m0 + r; if (gr >= M) gr = M - 1;
            async_copy16((char*)As + i * 16, A + (size_t)gr * IN_DIM + k0 + cl * 4);
        }
        // stage B: 256 rows x 32 f16 = 16 KB -> 1024 chunks, 4 issues
        #pragma unroll
        for (int it = 0; it < 4; ++it) {
            int i = it * 256 + tid;
            int r = i >> 2;
            int cp = i & 3;
            int cl = cp ^ (r & 3);
            async_copy16((char*)Bs + i * 16, Bt + (size_t)r * IN_DIM + k0 + cl * 8);
        }
        __syncthreads();

        const int kc = lane >> 4;        // k-chunk 0..3 (8 k each)
        f16x8 af[4];
        #pragma unroll
        for (int m = 0; m < 4; ++m) {
            int r = wm * 64 + m * 16 + (lane & 15);
            int p0 = (2 * kc) ^ (r & 7);
            int p1 = (2 * kc + 1) ^ (r & 7);
            f32x4 c0 = *(const f32x4*)((const char*)As + r * 128 + p0 * 16);
            f32x4 c1 = *(const f32x4*)((const char*)As + r * 128 + p1 * 16);
            f16x8 v = { (_Float16)c0[0], (_Float16)c0[1], (_Float16)c0[2], (_Float16)c0[3],
                        (_Float16)c1[0], (_Float16)c1[1], (_Float16)c1[2], (_Float16)c1[3] };
            af[m] = v;
        }
        f16x8 bf[8];
        #pragma unroll
        for (int n = 0; n < 8; ++n) {
            int r = wn * 128 + n * 16 + (lane & 15);
            bf[n] = *(const f16x8*)((const char*)Bs + r * 64 + ((kc ^ (r & 3)) * 16));
        }
        #pragma unroll
        for (int m = 0; m < 4; ++m)
            #pragma unroll
            for (int n = 0; n < 8; ++n)
                acc[m][n] = __builtin_amdgcn_mfma_f32_16x16x32_f16(af[m], bf[n], acc[m][n], 0, 0, 0);
        __syncthreads();
    }

    #pragma unroll
    for (int m = 0; m < 4; ++m)
        #pragma unroll
        for (int n = 0; n < 8; ++n)
            #pragma unroll
            for (int r = 0; r < 4; ++r) {
                int row = m0 + wm * 64 + m * 16 + (lane >> 4) * 4 + r;
                int col = wn * 128 + n * 16 + (lane & 15);
                if (row < M) C[(size_t)row * HID + col] = (_Float16)acc[m][n][r];
            }
}

// ---------------- GEMM2 (f16 A): C[M,N] = A[M,K] @ Bt[N,K]^T ----------------

template<int BN, int NR>
__global__ __launch_bounds__(256) void gemm_f16(const _Float16* __restrict__ A,
                                                const _Float16* __restrict__ Bt,
                                                _Float16* __restrict__ C,
                                                int M, int N, int K) {
    __shared__ _Float16 As[128 * 32];
    __shared__ _Float16 Bs[BN * 32];
    const int tid  = threadIdx.x;
    const int lane = tid & 63;
    const int wave = tid >> 6;
    const int wm = wave >> 1, wn = wave & 1;
    const int m0 = blockIdx.x * 128;
    const int n0 = blockIdx.y * BN;

    f32x4 acc[4][NR];
    #pragma unroll
    for (int i = 0; i < 4; ++i)
        #pragma unroll
        for (int j = 0; j < NR; ++j) acc[i][j] = (f32x4){0.f, 0.f, 0.f, 0.f};

    for (int k0 = 0; k0 < K; k0 += 32) {
        #pragma unroll
        for (int it = 0; it < 2; ++it) {
            int i = it * 256 + tid;
            int r = i >> 2;
            int q = (i & 3) ^ (r & 3);
            int gr = m0 + r; if (gr >= M) gr = M - 1;
            async_copy16((char*)As + i * 16, A + (size_t)gr * K + k0 + q * 8);
        }
        #pragma unroll
        for (int it = 0; it < BN / 64; ++it) {
            int i = it * 256 + tid;
            int r = i >> 2;
            int q = (i & 3) ^ (r & 3);
            async_copy16((char*)Bs + i * 16, Bt + (size_t)(n0 + r) * K + k0 + q * 8);
        }
        __syncthreads();

        f16x8 af[4], bf[NR];
        const int kc = lane >> 4;
        #pragma unroll
        for (int m = 0; m < 4; ++m) {
            int r = wm * 64 + m * 16 + (lane & 15);
            af[m] = *(const f16x8*)((const char*)As + r * 64 + ((kc ^ (r & 3)) * 16));
        }
        #pragma unroll
        for (int n = 0; n < NR; ++n) {
            int r = wn * (BN / 2) + n * 16 + (lane & 15);
            bf[n] = *(const f16x8*)((const char*)Bs + r * 64 + ((kc ^ (r & 3)) * 16));
        }
        #pragma unroll
        for (int m = 0; m < 4; ++m)
            #pragma unroll
            for (int n = 0; n < NR; ++n)
                acc[m][n] = __builtin_amdgcn_mfma_f32_16x16x32_f16(af[m], bf[n], acc[m][n], 0, 0, 0);
        __syncthreads();
    }

    #pragma unroll
    for (int m = 0; m < 4; ++m)
        #pragma unroll
        for (int n = 0; n < NR; ++n)
            #pragma unroll
            for (int r = 0; r < 4; ++r) {
                int row = m0 + wm * 64 + m * 16 + (lane >> 4) * 4 + r;
                int col = n0 + wn * (BN / 2) + n * 16 + (lane & 15);
                if (row < M) C[(size_t)row * N + col] = (_Float16)acc[m][n][r];
            }
}

// ---------------- SpMM layer 1: 2-edge parity, f16x8 gathers, masked tail ----------------
// Wave per node. Lanes 0-31: even edges, 32-63: odd edges. lane covers features fl*8..fl*8+7.

__global__ __launch_bounds__(256) void spmm_relu_f16(const int* __restrict__ offs,
                                                     const int2* __restrict__ pairs,
                                                     const _Float16* __restrict__ dense,
                                                     _Float16* __restrict__ out, int n) {
    int node = blockIdx.x * 4 + (threadIdx.x >> 6);
    if (node >= n) return;
    int lane = threadIdx.x & 63;
    int par = lane >> 5;
    int fl  = lane & 31;
    int beg = offs[node], end = offs[node + 1];
    const _Float16* dbase = dense + fl * 8;
    float a[8] = {};
    int k = beg;
    for (; k + 16 <= end; k += 16) {
        int2 pr[8];
        #pragma unroll
        for (int j = 0; j < 8; ++j) pr[j] = pairs[k + 2 * j + par];
        f16x8 p[8];
        #pragma unroll
        for (int j = 0; j < 8; ++j)
            p[j] = *(const f16x8*)(dbase + (size_t)pr[j].x * 256);
        #pragma unroll
        for (int j = 0; j < 8; ++j) {
            float v = __int_as_float(pr[j].y);
            #pragma unroll
            for (int q = 0; q < 8; ++q) a[q] = fmaf(v, (float)p[j][q], a[q]);
        }
    }
    if (k < end) {  // masked tail: covers remainder 1..15 with full MLP
        int2 pr[8];
        float vv[8];
        #pragma unroll
        for (int j = 0; j < 8; ++j) {
            int idx = k + 2 * j + par;
            int cidx = idx < end ? idx : end - 1;
            pr[j] = pairs[cidx];
            vv[j] = idx < end ? __int_as_float(pr[j].y) : 0.f;
        }
        f16x8 p[8];
        #pragma unroll
        for (int j = 0; j < 8; ++j)
            p[j] = *(const f16x8*)(dbase + (size_t)pr[j].x * 256);
        #pragma unroll
        for (int j = 0; j < 8; ++j) {
            #pragma unroll
            for (int q = 0; q < 8; ++q) a[q] = fmaf(vv[j], (float)p[j][q], a[q]);
        }
    }
    #pragma unroll
    for (int q = 0; q < 8; ++q) a[q] += __shfl_xor(a[q], 32);
    if (par == 0) {
        f16x8 o;
        #pragma unroll
        for (int q = 0; q < 8; ++q) o[q] = (_Float16)fmaxf(a[q], 0.f);
        *(f16x8*)(out + (size_t)node * 256 + fl * 8) = o;
    }
}

// ---------------- SpMM layer 2: 4-edge parity, f16x4 gathers, masked tail ----------------
// Lane covers features fl*4..fl*4+3 (fl=lane&15); par=lane>>4 picks edge residue mod 4.

__global__ __launch_bounds__(256) void spmm64_f16(const int* __restrict__ offs,
                                                  const int2* __restrict__ pairs,
                                                  const _Float16* __restrict__ dense,
                                                  float* __restrict__ out, int n) {
    int node = blockIdx.x * 4 + (threadIdx.x >> 6);
    if (node >= n) return;
    int lane = threadIdx.x & 63;
    int par = lane >> 4;
    int fl  = lane & 15;
    int beg = offs[node], end = offs[node + 1];
    const _Float16* dbase = dense + fl * 4;
    float a[4] = {};
    int k = beg;
    for (; k + 32 <= end; k += 32) {
        int2 pr[8];
        #pragma unroll
        for (int j = 0; j < 8; ++j) pr[j] = pairs[k + 4 * j + par];
        f16x4 p[8];
        #pragma unroll
        for (int j = 0; j < 8; ++j)
            p[j] = *(const f16x4*)(dbase + (size_t)pr[j].x * 64);
        #pragma unroll
        for (int j = 0; j < 8; ++j) {
            float v = __int_as_float(pr[j].y);
            #pragma unroll
            for (int q = 0; q < 4; ++q) a[q] = fmaf(v, (float)p[j][q], a[q]);
        }
    }
    if (k < end) {  // masked tail: remainder 1..31
        int2 pr[8];
        float vv[8];
        #pragma unroll
        for (int j = 0; j < 8; ++j) {
            int idx = k + 4 * j + par;
            int cidx = idx < end ? idx : end - 1;
            pr[j] = pairs[cidx];
            vv[j] = idx < end ? __int_as_float(pr[j].y) : 0.f;
        }
        f16x4 p[8];
        #pragma unroll
        for (int j = 0; j < 8; ++j)
            p[j] = *(const f16x4*)(dbase + (size_t)pr[j].x * 64);
        #pragma unroll
        for (int j = 0; j < 8; ++j) {
            #pragma unroll
            for (int q = 0; q < 4; ++q) a[q] = fmaf(vv[j], (float)p[j][q], a[q]);
        }
    }
    #pragma unroll
    for (int q = 0; q < 4; ++q) {
        a[q] += __shfl_xor(a[q], 16);
        a[q] += __shfl_xor(a[q], 32);
    }
    if (par == 0) {
        float4 o = make_float4(a[0], a[1], a[2], a[3]);
        *(float4*)(out + (size_t)node * 64 + fl * 4) = o;
    }
}

// ---------------- launch ----------------

extern "C" void kernel_launch(void* const* d_in, const int* in_sizes, int n_in,
                              void* d_out, int out_size, void* d_ws, size_t ws_size,
                              hipStream_t stream) {
    const float* x    = (const float*)d_in[0];
    const int*   esrc = (const int*)d_in[1];
    const int*   edst = (const int*)d_in[2];
    const float* eval = (const float*)d_in[3];
    const float* w1   = (const float*)d_in[4];
    const float* w2   = (const float*)d_in[5];
    float* out = (float*)d_out;

    char* ws = (char*)d_ws;
    _Float16* pre     = (_Float16*)(ws + 0);            //  51,200,000 B
    _Float16* h       = (_Float16*)(ws + 51200000);     //  51,200,000 B
    int2*     pairs   = (int2*)(ws + 102400000);        //  25,600,000 B
    int2*     pairs_t = (int2*)(ws + 128000000);        //  25,600,000 B
    int*      srcs_t  = (int*)(ws + 153600000);         //  12,800,000 B
    int*      counts  = (int*)(ws + 166400000);         //     400,000 B
    int*      offs    = (int*)(ws + 166800000);         //     400,128 B
    int*      bc      = (int*)(ws + 167200128);         //       1,024 B
    _Float16* w1t     = (_Float16*)(ws + 167201152);    //     262,144 B
    _Float16* w2t     = (_Float16*)(ws + 167463296);    //      32,768 B
    _Float16* h2 = pre;                                 // pre dead after spmm1

    hipMemsetAsync(counts, 0, NN * sizeof(int), stream);
    count_kernel<<<(NE + 255) / 256, 256, 0, stream>>>(esrc, counts, NE);
    scan_kernel<<<1, 1024, 0, stream>>>((const int4*)counts, offs, NN / 4, NN);
    init_bc_kernel<<<1, 256, 0, stream>>>(offs, bc);
    const int nblk = 1024, epb = (NE + nblk - 1) / nblk;
    bin_kernel<<<nblk, 256, 0, stream>>>(esrc, edst, eval, bc, srcs_t, pairs_t, NE, epb);
    csr_kernel<<<NB, 1024, 0, stream>>>(offs, srcs_t, pairs_t, pairs, NN);

    transpose_cast<<<(IN_DIM * HID + 255) / 256, 256, 0, stream>>>(w1, w1t, IN_DIM, HID);
    transpose_cast<<<(HID * OUTD + 255) / 256, 256, 0, stream>>>(w2, w2t, HID, OUTD);

    gemm1_f32a<<<(NN + 127) / 128, 256, 0, stream>>>(x, w1t, pre, NN);

    spmm_relu_f16<<<(NN + 3) / 4, 256, 0, stream>>>(offs, pairs, pre, h, NN);

    dim3 g2((NN + 127) / 128, 1);
    gemm_f16<64, 2><<<g2, 256, 0, stream>>>(h, w2t, h2, NN, OUTD, HID);

    spmm64_f16<<<(NN + 3) / 4, 256, 0, stream>>>(offs, pairs, h2, out, NN);
}

// Round 6
// 495.637 us; speedup vs baseline: 2.9273x; 1.4270x over previous
//
#include <hip/hip_runtime.h>

#define NN 100000
#define NE 3200000
#define IN_DIM 512
#define HID 256
#define OUTD 64
#define NB 196            // ceil(100000/512) coarse buckets of 512 srcs
#define CAP 20480         // fixed slot capacity per bucket (max bucket ~17k)
#define EPB 3125          // edges per bin block (NE / 1024)

typedef _Float16 f16x8 __attribute__((ext_vector_type(8)));
typedef _Float16 f16x4 __attribute__((ext_vector_type(4)));
typedef float f32x4 __attribute__((ext_vector_type(4)));

__device__ __forceinline__ void async_copy16(void* lds, const void* g) {
    __builtin_amdgcn_global_load_lds(
        (const __attribute__((address_space(1))) void*)g,
        (__attribute__((address_space(3))) void*)lds, 16, 0, 0);
}

// ---------------- CSR build (two-level bucket sort, no global count/scan) ----------------

__global__ void init_cursor_kernel(int* __restrict__ cursor) {
    int t = threadIdx.x;
    if (t < NB) cursor[t] = t * CAP;
}

// bin: LDS-stage a chunk of edges, histogram to 196 buckets, reserve runs, distribute.
__global__ __launch_bounds__(256) void bin_kernel(const int* __restrict__ src,
                                                  const int* __restrict__ dst,
                                                  const float* __restrict__ val,
                                                  int* __restrict__ cursor,
                                                  int* __restrict__ srcs_tmp,
                                                  int2* __restrict__ pairs_tmp,
                                                  int E) {
    __shared__ int s_src[EPB];
    __shared__ int s_dst[EPB];
    __shared__ int s_val[EPB];
    __shared__ int hist[NB];
    __shared__ int base[NB];
    const int t = threadIdx.x;
    const int lo = blockIdx.x * EPB;
    const int cnt = min(E - lo, EPB);
    for (int i = t; i < NB; i += 256) hist[i] = 0;
    for (int i = t; i < cnt; i += 256) {
        s_src[i] = src[lo + i];
        s_dst[i] = dst[lo + i];
        s_val[i] = __float_as_int(val[lo + i]);
    }
    __syncthreads();
    for (int i = t; i < cnt; i += 256) atomicAdd(&hist[s_src[i] >> 9], 1);
    __syncthreads();
    for (int i = t; i < NB; i += 256) {
        base[i] = atomicAdd(&cursor[i], hist[i]);
        hist[i] = 0;
    }
    __syncthreads();
    for (int i = t; i < cnt; i += 256) {
        int s = s_src[i];
        int b = s >> 9;
        int l = atomicAdd(&hist[b], 1);
        int pos = base[b] + l;
        srcs_tmp[pos] = s;
        pairs_tmp[pos] = make_int2(s_dst[i], s_val[i]);
    }
}

// tiny: bucket sizes -> exclusive scan -> global bucket bases; also offs[NN]
__global__ void bucket_scan_kernel(const int* __restrict__ cursor,
                                   int* __restrict__ bbase, int* __restrict__ offs) {
    __shared__ int sz[NB];
    int t = threadIdx.x;
    if (t < NB) sz[t] = cursor[t] - t * CAP;
    __syncthreads();
    if (t == 0) {
        int acc = 0;
        for (int i = 0; i < NB; ++i) { bbase[i] = acc; acc += sz[i]; }
        bbase[NB] = acc;
        offs[NN] = acc;
    }
}

// finalize: per bucket, LDS hist over 512 srcs + block scan -> offs + ordered pairs
#define CSR_LDS 18432
__global__ __launch_bounds__(1024) void csr_kernel(const int* __restrict__ cursor,
                                                   const int* __restrict__ bbase,
                                                   const int* __restrict__ srcs_tmp,
                                                   const int2* __restrict__ pairs_tmp,
                                                   int* __restrict__ offs,
                                                   int2* __restrict__ pairs) {
    __shared__ int ssrc[CSR_LDS];
    __shared__ int cnt[512];
    __shared__ int wsum[8];
    const int b = blockIdx.x;
    const int t = threadIdx.x;
    const int s0 = b << 9;
    const int base = bbase[b];
    const int n_b = cursor[b] - b * CAP;
    const int tlo = b * CAP;
    if (t < 512) cnt[t] = 0;
    __syncthreads();
    for (int i = t; i < n_b; i += 1024) {
        int s = srcs_tmp[tlo + i] - s0;
        ssrc[i] = s;
        atomicAdd(&cnt[s], 1);
    }
    __syncthreads();
    int my = 0, incl = 0;
    if (t < 512) {
        my = cnt[t];
        incl = my;
        #pragma unroll
        for (int d = 1; d < 64; d <<= 1) {
            int y = __shfl_up(incl, d);
            if ((t & 63) >= d) incl += y;
        }
        if ((t & 63) == 63) wsum[t >> 6] = incl;
    }
    __syncthreads();
    if (t == 0) {
        int acc = 0;
        #pragma unroll
        for (int i = 0; i < 8; ++i) { int v = wsum[i]; wsum[i] = acc; acc += v; }
    }
    __syncthreads();
    if (t < 512) {
        int excl = base + incl - my + wsum[t >> 6];
        int s = s0 + t;
        if (s < NN) offs[s] = excl;
        cnt[t] = excl;               // becomes the write cursor
    }
    __syncthreads();
    for (int i = t; i < n_b; i += 1024) {
        int s = ssrc[i];
        int p = atomicAdd(&cnt[s], 1);
        pairs[p] = pairs_tmp[tlo + i];
    }
}

// ---------------- weight transpose-cast (both weights, one launch) ----------------

__global__ void transpose_cast2(const float* __restrict__ w1, const float* __restrict__ w2,
                                _Float16* __restrict__ w1t, _Float16* __restrict__ w2t) {
    int idx = blockIdx.x * blockDim.x + threadIdx.x;
    if (idx < IN_DIM * HID) {
        int k = idx / HID, n = idx % HID;
        w1t[(size_t)n * IN_DIM + k] = (_Float16)w1[idx];
    } else if (idx < IN_DIM * HID + HID * OUTD) {
        int j = idx - IN_DIM * HID;
        int k = j / OUTD, n = j % OUTD;
        w2t[(size_t)n * HID + k] = (_Float16)w2[j];
    }
}

// ---------------- GEMM1: pre[M,256] = x[M,512](f32) @ w1t[256,512]^T ----------------

__global__ __launch_bounds__(256) void gemm1_f32a(const float* __restrict__ A,
                                                  const _Float16* __restrict__ Bt,
                                                  _Float16* __restrict__ C,
                                                  int M) {
    __shared__ float    As[128 * 32];    // 16 KB
    __shared__ _Float16 Bs[256 * 32];    // 16 KB
    const int tid  = threadIdx.x;
    const int lane = tid & 63;
    const int wave = tid >> 6;
    const int wm = wave >> 1, wn = wave & 1;
    const int m0 = blockIdx.x * 128;

    f32x4 acc[4][8];
    #pragma unroll
    for (int i = 0; i < 4; ++i)
        #pragma unroll
        for (int j = 0; j < 8; ++j) acc[i][j] = (f32x4){0.f, 0.f, 0.f, 0.f};

    for (int k0 = 0; k0 < IN_DIM; k0 += 32) {
        #pragma unroll
        for (int it = 0; it < 4; ++it) {
            int i = it * 256 + tid;
            int r = i >> 3;
            int cp = i & 7;
            int cl = cp ^ (r & 7);
            int gr = m0 + r; if (gr >= M) gr = M - 1;
            async_copy16((char*)As + i * 16, A + (size_t)gr * IN_DIM + k0 + cl * 4);
        }
        #pragma unroll
        for (int it = 0; it < 4; ++it) {
            int i = it * 256 + tid;
            int r = i >> 2;
            int cp = i & 3;
            int cl = cp ^ (r & 3);
            async_copy16((char*)Bs + i * 16, Bt + (size_t)r * IN_DIM + k0 + cl * 8);
        }
        __syncthreads();

        const int kc = lane >> 4;
        f16x8 af[4];
        #pragma unroll
        for (int m = 0; m < 4; ++m) {
            int r = wm * 64 + m * 16 + (lane & 15);
            int p0 = (2 * kc) ^ (r & 7);
            int p1 = (2 * kc + 1) ^ (r & 7);
            f32x4 c0 = *(const f32x4*)((const char*)As + r * 128 + p0 * 16);
            f32x4 c1 = *(const f32x4*)((const char*)As + r * 128 + p1 * 16);
            f16x8 v = { (_Float16)c0[0], (_Float16)c0[1], (_Float16)c0[2], (_Float16)c0[3],
                        (_Float16)c1[0], (_Float16)c1[1], (_Float16)c1[2], (_Float16)c1[3] };
            af[m] = v;
        }
        f16x8 bf[8];
        #pragma unroll
        for (int n = 0; n < 8; ++n) {
            int r = wn * 128 + n * 16 + (lane & 15);
            bf[n] = *(const f16x8*)((const char*)Bs + r * 64 + ((kc ^ (r & 3)) * 16));
        }
        #pragma unroll
        for (int m = 0; m < 4; ++m)
            #pragma unroll
            for (int n = 0; n < 8; ++n)
                acc[m][n] = __builtin_amdgcn_mfma_f32_16x16x32_f16(af[m], bf[n], acc[m][n], 0, 0, 0);
        __syncthreads();
    }

    #pragma unroll
    for (int m = 0; m < 4; ++m)
        #pragma unroll
        for (int n = 0; n < 8; ++n)
            #pragma unroll
            for (int r = 0; r < 4; ++r) {
                int row = m0 + wm * 64 + m * 16 + (lane >> 4) * 4 + r;
                int col = wn * 128 + n * 16 + (lane & 15);
                if (row < M) C[(size_t)row * HID + col] = (_Float16)acc[m][n][r];
            }
}

// ---------------- GEMM2 (f16 A): C[M,N] = A[M,K] @ Bt[N,K]^T ----------------

template<int BN, int NR>
__global__ __launch_bounds__(256) void gemm_f16(const _Float16* __restrict__ A,
                                                const _Float16* __restrict__ Bt,
                                                _Float16* __restrict__ C,
                                                int M, int N, int K) {
    __shared__ _Float16 As[128 * 32];
    __shared__ _Float16 Bs[BN * 32];
    const int tid  = threadIdx.x;
    const int lane = tid & 63;
    const int wave = tid >> 6;
    const int wm = wave >> 1, wn = wave & 1;
    const int m0 = blockIdx.x * 128;
    const int n0 = blockIdx.y * BN;

    f32x4 acc[4][NR];
    #pragma unroll
    for (int i = 0; i < 4; ++i)
        #pragma unroll
        for (int j = 0; j < NR; ++j) acc[i][j] = (f32x4){0.f, 0.f, 0.f, 0.f};

    for (int k0 = 0; k0 < K; k0 += 32) {
        #pragma unroll
        for (int it = 0; it < 2; ++it) {
            int i = it * 256 + tid;
            int r = i >> 2;
            int q = (i & 3) ^ (r & 3);
            int gr = m0 + r; if (gr >= M) gr = M - 1;
            async_copy16((char*)As + i * 16, A + (size_t)gr * K + k0 + q * 8);
        }
        #pragma unroll
        for (int it = 0; it < BN / 64; ++it) {
            int i = it * 256 + tid;
            int r = i >> 2;
            int q = (i & 3) ^ (r & 3);
            async_copy16((char*)Bs + i * 16, Bt + (size_t)(n0 + r) * K + k0 + q * 8);
        }
        __syncthreads();

        f16x8 af[4], bf[NR];
        const int kc = lane >> 4;
        #pragma unroll
        for (int m = 0; m < 4; ++m) {
            int r = wm * 64 + m * 16 + (lane & 15);
            af[m] = *(const f16x8*)((const char*)As + r * 64 + ((kc ^ (r & 3)) * 16));
        }
        #pragma unroll
        for (int n = 0; n < NR; ++n) {
            int r = wn * (BN / 2) + n * 16 + (lane & 15);
            bf[n] = *(const f16x8*)((const char*)Bs + r * 64 + ((kc ^ (r & 3)) * 16));
        }
        #pragma unroll
        for (int m = 0; m < 4; ++m)
            #pragma unroll
            for (int n = 0; n < NR; ++n)
                acc[m][n] = __builtin_amdgcn_mfma_f32_16x16x32_f16(af[m], bf[n], acc[m][n], 0, 0, 0);
        __syncthreads();
    }

    #pragma unroll
    for (int m = 0; m < 4; ++m)
        #pragma unroll
        for (int n = 0; n < NR; ++n)
            #pragma unroll
            for (int r = 0; r < 4; ++r) {
                int row = m0 + wm * 64 + m * 16 + (lane >> 4) * 4 + r;
                int col = n0 + wn * (BN / 2) + n * 16 + (lane & 15);
                if (row < M) C[(size_t)row * N + col] = (_Float16)acc[m][n][r];
            }
}

// ---------------- SpMM layer 1: 2-edge parity, f16x8 gathers, masked tail ----------------

__global__ __launch_bounds__(256) void spmm_relu_f16(const int* __restrict__ offs,
                                                     const int2* __restrict__ pairs,
                                                     const _Float16* __restrict__ dense,
                                                     _Float16* __restrict__ out, int n) {
    int node = blockIdx.x * 4 + (threadIdx.x >> 6);
    if (node >= n) return;
    int lane = threadIdx.x & 63;
    int par = lane >> 5;
    int fl  = lane & 31;
    int beg = offs[node], end = offs[node + 1];
    const _Float16* dbase = dense + fl * 8;
    float a[8] = {};
    int k = beg;
    for (; k + 16 <= end; k += 16) {
        int2 pr[8];
        #pragma unroll
        for (int j = 0; j < 8; ++j) pr[j] = pairs[k + 2 * j + par];
        f16x8 p[8];
        #pragma unroll
        for (int j = 0; j < 8; ++j)
            p[j] = *(const f16x8*)(dbase + (size_t)pr[j].x * 256);
        #pragma unroll
        for (int j = 0; j < 8; ++j) {
            float v = __int_as_float(pr[j].y);
            #pragma unroll
            for (int q = 0; q < 8; ++q) a[q] = fmaf(v, (float)p[j][q], a[q]);
        }
    }
    if (k < end) {
        int2 pr[8];
        float vv[8];
        #pragma unroll
        for (int j = 0; j < 8; ++j) {
            int idx = k + 2 * j + par;
            int cidx = idx < end ? idx : end - 1;
            pr[j] = pairs[cidx];
            vv[j] = idx < end ? __int_as_float(pr[j].y) : 0.f;
        }
        f16x8 p[8];
        #pragma unroll
        for (int j = 0; j < 8; ++j)
            p[j] = *(const f16x8*)(dbase + (size_t)pr[j].x * 256);
        #pragma unroll
        for (int j = 0; j < 8; ++j) {
            #pragma unroll
            for (int q = 0; q < 8; ++q) a[q] = fmaf(vv[j], (float)p[j][q], a[q]);
        }
    }
    #pragma unroll
    for (int q = 0; q < 8; ++q) a[q] += __shfl_xor(a[q], 32);
    if (par == 0) {
        f16x8 o;
        #pragma unroll
        for (int q = 0; q < 8; ++q) o[q] = (_Float16)fmaxf(a[q], 0.f);
        *(f16x8*)(out + (size_t)node * 256 + fl * 8) = o;
    }
}

// ---------------- SpMM layer 2: 4-edge parity, f16x4 gathers, masked tail ----------------

__global__ __launch_bounds__(256) void spmm64_f16(const int* __restrict__ offs,
                                                  const int2* __restrict__ pairs,
                                                  const _Float16* __restrict__ dense,
                                                  float* __restrict__ out, int n) {
    int node = blockIdx.x * 4 + (threadIdx.x >> 6);
    if (node >= n) return;
    int lane = threadIdx.x & 63;
    int par = lane >> 4;
    int fl  = lane & 15;
    int beg = offs[node], end = offs[node + 1];
    const _Float16* dbase = dense + fl * 4;
    float a[4] = {};
    int k = beg;
    for (; k + 32 <= end; k += 32) {
        int2 pr[8];
        #pragma unroll
        for (int j = 0; j < 8; ++j) pr[j] = pairs[k + 4 * j + par];
        f16x4 p[8];
        #pragma unroll
        for (int j = 0; j < 8; ++j)
            p[j] = *(const f16x4*)(dbase + (size_t)pr[j].x * 64);
        #pragma unroll
        for (int j = 0; j < 8; ++j) {
            float v = __int_as_float(pr[j].y);
            #pragma unroll
            for (int q = 0; q < 4; ++q) a[q] = fmaf(v, (float)p[j][q], a[q]);
        }
    }
    if (k < end) {
        int2 pr[8];
        float vv[8];
        #pragma unroll
        for (int j = 0; j < 8; ++j) {
            int idx = k + 4 * j + par;
            int cidx = idx < end ? idx : end - 1;
            pr[j] = pairs[cidx];
            vv[j] = idx < end ? __int_as_float(pr[j].y) : 0.f;
        }
        f16x4 p[8];
        #pragma unroll
        for (int j = 0; j < 8; ++j)
            p[j] = *(const f16x4*)(dbase + (size_t)pr[j].x * 64);
        #pragma unroll
        for (int j = 0; j < 8; ++j) {
            #pragma unroll
            for (int q = 0; q < 4; ++q) a[q] = fmaf(vv[j], (float)p[j][q], a[q]);
        }
    }
    #pragma unroll
    for (int q = 0; q < 4; ++q) {
        a[q] += __shfl_xor(a[q], 16);
        a[q] += __shfl_xor(a[q], 32);
    }
    if (par == 0) {
        float4 o = make_float4(a[0], a[1], a[2], a[3]);
        *(float4*)(out + (size_t)node * 64 + fl * 4) = o;
    }
}

// ---------------- launch ----------------

extern "C" void kernel_launch(void* const* d_in, const int* in_sizes, int n_in,
                              void* d_out, int out_size, void* d_ws, size_t ws_size,
                              hipStream_t stream) {
    const float* x    = (const float*)d_in[0];
    const int*   esrc = (const int*)d_in[1];
    const int*   edst = (const int*)d_in[2];
    const float* eval = (const float*)d_in[3];
    const float* w1   = (const float*)d_in[4];
    const float* w2   = (const float*)d_in[5];
    float* out = (float*)d_out;

    char* ws = (char*)d_ws;
    _Float16* pre     = (_Float16*)(ws + 0);            //  51,200,000 B
    _Float16* h       = (_Float16*)(ws + 51200000);     //  51,200,000 B
    int2*     pairs   = (int2*)(ws + 102400000);        //  25,600,000 B
    int2*     pairs_t = (int2*)(ws + 128000000);        //  32,112,640 B (196*CAP*8)
    int*      srcs_t  = (int*)(ws + 160112640);         //  16,056,320 B (196*CAP*4)
    int*      cursor  = (int*)(ws + 176168960);         //       1,024 B
    int*      bbase   = (int*)(ws + 176169984);         //       1,024 B
    int*      offs    = (int*)(ws + 176171008);         //     400,128 B
    _Float16* w1t     = (_Float16*)(ws + 176571136);    //     262,144 B
    _Float16* w2t     = (_Float16*)(ws + 176833280);    //      32,768 B
    _Float16* h2 = pre;                                 // pre dead after spmm1

    init_cursor_kernel<<<1, 256, 0, stream>>>(cursor);
    bin_kernel<<<1024, 256, 0, stream>>>(esrc, edst, eval, cursor, srcs_t, pairs_t, NE);
    bucket_scan_kernel<<<1, 256, 0, stream>>>(cursor, bbase, offs);
    csr_kernel<<<NB, 1024, 0, stream>>>(cursor, bbase, srcs_t, pairs_t, offs, pairs);

    transpose_cast2<<<(IN_DIM * HID + HID * OUTD + 255) / 256, 256, 0, stream>>>(w1, w2, w1t, w2t);

    gemm1_f32a<<<(NN + 127) / 128, 256, 0, stream>>>(x, w1t, pre, NN);

    spmm_relu_f16<<<(NN + 3) / 4, 256, 0, stream>>>(offs, pairs, pre, h, NN);

    dim3 g2((NN + 127) / 128, 1);
    gemm_f16<64, 2><<<g2, 256, 0, stream>>>(h, w2t, h2, NN, OUTD, HID);

    spmm64_f16<<<(NN + 3) / 4, 256, 0, stream>>>(offs, pairs, h2, out, NN);
}

// Round 7
// 475.363 us; speedup vs baseline: 3.0521x; 1.0426x over previous
//
#include <hip/hip_runtime.h>

#define NN 100000
#define NE 3200000
#define IN_DIM 512
#define HID 256
#define OUTD 64
#define NB 196            // ceil(100000/512) coarse buckets of 512 srcs
#define CAP 20480         // fixed slot capacity per bucket (max bucket ~17k)
#define EPB 3125          // edges per bin block (NE / 1024)

typedef _Float16 f16x8 __attribute__((ext_vector_type(8)));
typedef _Float16 f16x4 __attribute__((ext_vector_type(4)));
typedef float f32x4 __attribute__((ext_vector_type(4)));

__device__ __forceinline__ void async_copy16(void* lds, const void* g) {
    __builtin_amdgcn_global_load_lds(
        (const __attribute__((address_space(1))) void*)g,
        (__attribute__((address_space(3))) void*)lds, 16, 0, 0);
}

// ---------------- CSR build (two-level bucket sort, no global count/scan) ----------------

__global__ void init_cursor_kernel(int* __restrict__ cursor) {
    int t = threadIdx.x;
    if (t < NB) cursor[t] = t * CAP;
}

__global__ __launch_bounds__(256) void bin_kernel(const int* __restrict__ src,
                                                  const int* __restrict__ dst,
                                                  const float* __restrict__ val,
                                                  int* __restrict__ cursor,
                                                  int* __restrict__ srcs_tmp,
                                                  int2* __restrict__ pairs_tmp,
                                                  int E) {
    __shared__ int s_src[EPB];
    __shared__ int s_dst[EPB];
    __shared__ int s_val[EPB];
    __shared__ int hist[NB];
    __shared__ int base[NB];
    const int t = threadIdx.x;
    const int lo = blockIdx.x * EPB;
    const int cnt = min(E - lo, EPB);
    for (int i = t; i < NB; i += 256) hist[i] = 0;
    for (int i = t; i < cnt; i += 256) {
        s_src[i] = src[lo + i];
        s_dst[i] = dst[lo + i];
        s_val[i] = __float_as_int(val[lo + i]);
    }
    __syncthreads();
    for (int i = t; i < cnt; i += 256) atomicAdd(&hist[s_src[i] >> 9], 1);
    __syncthreads();
    for (int i = t; i < NB; i += 256) {
        base[i] = atomicAdd(&cursor[i], hist[i]);
        hist[i] = 0;
    }
    __syncthreads();
    for (int i = t; i < cnt; i += 256) {
        int s = s_src[i];
        int b = s >> 9;
        int l = atomicAdd(&hist[b], 1);
        int pos = base[b] + l;
        srcs_tmp[pos] = s;
        pairs_tmp[pos] = make_int2(s_dst[i], s_val[i]);
    }
}

__global__ void bucket_scan_kernel(const int* __restrict__ cursor,
                                   int* __restrict__ bbase, int* __restrict__ offs) {
    __shared__ int sz[NB];
    int t = threadIdx.x;
    if (t < NB) sz[t] = cursor[t] - t * CAP;
    __syncthreads();
    if (t == 0) {
        int acc = 0;
        for (int i = 0; i < NB; ++i) { bbase[i] = acc; acc += sz[i]; }
        bbase[NB] = acc;
        offs[NN] = acc;
    }
}

#define CSR_LDS 18432
__global__ __launch_bounds__(1024) void csr_kernel(const int* __restrict__ cursor,
                                                   const int* __restrict__ bbase,
                                                   const int* __restrict__ srcs_tmp,
                                                   const int2* __restrict__ pairs_tmp,
                                                   int* __restrict__ offs,
                                                   int2* __restrict__ pairs) {
    __shared__ int ssrc[CSR_LDS];
    __shared__ int cnt[512];
    __shared__ int wsum[8];
    const int b = blockIdx.x;
    const int t = threadIdx.x;
    const int s0 = b << 9;
    const int base = bbase[b];
    const int n_b = cursor[b] - b * CAP;
    const int tlo = b * CAP;
    if (t < 512) cnt[t] = 0;
    __syncthreads();
    for (int i = t; i < n_b; i += 1024) {
        int s = srcs_tmp[tlo + i] - s0;
        ssrc[i] = s;
        atomicAdd(&cnt[s], 1);
    }
    __syncthreads();
    int my = 0, incl = 0;
    if (t < 512) {
        my = cnt[t];
        incl = my;
        #pragma unroll
        for (int d = 1; d < 64; d <<= 1) {
            int y = __shfl_up(incl, d);
            if ((t & 63) >= d) incl += y;
        }
        if ((t & 63) == 63) wsum[t >> 6] = incl;
    }
    __syncthreads();
    if (t == 0) {
        int acc = 0;
        #pragma unroll
        for (int i = 0; i < 8; ++i) { int v = wsum[i]; wsum[i] = acc; acc += v; }
    }
    __syncthreads();
    if (t < 512) {
        int excl = base + incl - my + wsum[t >> 6];
        int s = s0 + t;
        if (s < NN) offs[s] = excl;
        cnt[t] = excl;
    }
    __syncthreads();
    for (int i = t; i < n_b; i += 1024) {
        int s = ssrc[i];
        int p = atomicAdd(&cnt[s], 1);
        pairs[p] = pairs_tmp[tlo + i];
    }
}

// ---------------- weight transpose-cast (both weights, one launch) ----------------

__global__ void transpose_cast2(const float* __restrict__ w1, const float* __restrict__ w2,
                                _Float16* __restrict__ w1t, _Float16* __restrict__ w2t) {
    int idx = blockIdx.x * blockDim.x + threadIdx.x;
    if (idx < IN_DIM * HID) {
        int k = idx / HID, n = idx % HID;
        w1t[(size_t)n * IN_DIM + k] = (_Float16)w1[idx];
    } else if (idx < IN_DIM * HID + HID * OUTD) {
        int j = idx - IN_DIM * HID;
        int k = j / OUTD, n = j % OUTD;
        w2t[(size_t)n * HID + k] = (_Float16)w2[j];
    }
}

// ---------------- GEMM1: pre[M,256] = x[M,512](f32) @ w1t[256,512]^T ----------------

__global__ __launch_bounds__(256) void gemm1_f32a(const float* __restrict__ A,
                                                  const _Float16* __restrict__ Bt,
                                                  _Float16* __restrict__ C,
                                                  int M) {
    __shared__ float    As[128 * 32];    // 16 KB
    __shared__ _Float16 Bs[256 * 32];    // 16 KB
    const int tid  = threadIdx.x;
    const int lane = tid & 63;
    const int wave = tid >> 6;
    const int wm = wave >> 1, wn = wave & 1;
    const int m0 = blockIdx.x * 128;

    f32x4 acc[4][8];
    #pragma unroll
    for (int i = 0; i < 4; ++i)
        #pragma unroll
        for (int j = 0; j < 8; ++j) acc[i][j] = (f32x4){0.f, 0.f, 0.f, 0.f};

    for (int k0 = 0; k0 < IN_DIM; k0 += 32) {
        #pragma unroll
        for (int it = 0; it < 4; ++it) {
            int i = it * 256 + tid;
            int r = i >> 3;
            int cp = i & 7;
            int cl = cp ^ (r & 7);
            int gr = m0 + r; if (gr >= M) gr = M - 1;
            async_copy16((char*)As + i * 16, A + (size_t)gr * IN_DIM + k0 + cl * 4);
        }
        #pragma unroll
        for (int it = 0; it < 4; ++it) {
            int i = it * 256 + tid;
            int r = i >> 2;
            int cp = i & 3;
            int cl = cp ^ (r & 3);
            async_copy16((char*)Bs + i * 16, Bt + (size_t)r * IN_DIM + k0 + cl * 8);
        }
        __syncthreads();

        const int kc = lane >> 4;
        f16x8 af[4];
        #pragma unroll
        for (int m = 0; m < 4; ++m) {
            int r = wm * 64 + m * 16 + (lane & 15);
            int p0 = (2 * kc) ^ (r & 7);
            int p1 = (2 * kc + 1) ^ (r & 7);
            f32x4 c0 = *(const f32x4*)((const char*)As + r * 128 + p0 * 16);
            f32x4 c1 = *(const f32x4*)((const char*)As + r * 128 + p1 * 16);
            f16x8 v = { (_Float16)c0[0], (_Float16)c0[1], (_Float16)c0[2], (_Float16)c0[3],
                        (_Float16)c1[0], (_Float16)c1[1], (_Float16)c1[2], (_Float16)c1[3] };
            af[m] = v;
        }
        f16x8 bf[8];
        #pragma unroll
        for (int n = 0; n < 8; ++n) {
            int r = wn * 128 + n * 16 + (lane & 15);
            bf[n] = *(const f16x8*)((const char*)Bs + r * 64 + ((kc ^ (r & 3)) * 16));
        }
        #pragma unroll
        for (int m = 0; m < 4; ++m)
            #pragma unroll
            for (int n = 0; n < 8; ++n)
                acc[m][n] = __builtin_amdgcn_mfma_f32_16x16x32_f16(af[m], bf[n], acc[m][n], 0, 0, 0);
        __syncthreads();
    }

    #pragma unroll
    for (int m = 0; m < 4; ++m)
        #pragma unroll
        for (int n = 0; n < 8; ++n)
            #pragma unroll
            for (int r = 0; r < 4; ++r) {
                int row = m0 + wm * 64 + m * 16 + (lane >> 4) * 4 + r;
                int col = wn * 128 + n * 16 + (lane & 15);
                if (row < M) C[(size_t)row * HID + col] = (_Float16)acc[m][n][r];
            }
}

// ---------------- fused SpMM1 + ReLU + GEMM2 ----------------
// 16 nodes/block (4 waves x 4 nodes). Gather loop identical to round-6 spmm_relu.
// ReLU'd 256-rows land in LDS k-chunk-major; MFMA epilogue computes h2 = h_tile @ w2.

__global__ __launch_bounds__(256) void spmm_relu_mm2(const int* __restrict__ offs,
                                                     const int2* __restrict__ pairs,
                                                     const _Float16* __restrict__ dense,
                                                     const _Float16* __restrict__ w2t,
                                                     _Float16* __restrict__ h2, int n) {
    __shared__ _Float16 hl[32][16][8];   // [k-chunk][node][8 f16] = 8 KB
    const int tid  = threadIdx.x;
    const int lane = tid & 63;
    const int wid  = tid >> 6;
    const int par  = lane >> 5;
    const int fl   = lane & 31;
    const int nbase = blockIdx.x * 16;
    const _Float16* dbase = dense + fl * 8;

    #pragma unroll 1
    for (int i = 0; i < 4; ++i) {
        const int node = nbase + wid * 4 + i;
        const int beg = offs[node], end = offs[node + 1];
        float a[8] = {};
        int k = beg;
        for (; k + 16 <= end; k += 16) {
            int2 pr[8];
            #pragma unroll
            for (int j = 0; j < 8; ++j) pr[j] = pairs[k + 2 * j + par];
            f16x8 p[8];
            #pragma unroll
            for (int j = 0; j < 8; ++j)
                p[j] = *(const f16x8*)(dbase + (size_t)pr[j].x * 256);
            #pragma unroll
            for (int j = 0; j < 8; ++j) {
                float v = __int_as_float(pr[j].y);
                #pragma unroll
                for (int q = 0; q < 8; ++q) a[q] = fmaf(v, (float)p[j][q], a[q]);
            }
        }
        if (k < end) {
            int2 pr[8];
            float vv[8];
            #pragma unroll
            for (int j = 0; j < 8; ++j) {
                int idx = k + 2 * j + par;
                int cidx = idx < end ? idx : end - 1;
                pr[j] = pairs[cidx];
                vv[j] = idx < end ? __int_as_float(pr[j].y) : 0.f;
            }
            f16x8 p[8];
            #pragma unroll
            for (int j = 0; j < 8; ++j)
                p[j] = *(const f16x8*)(dbase + (size_t)pr[j].x * 256);
            #pragma unroll
            for (int j = 0; j < 8; ++j) {
                #pragma unroll
                for (int q = 0; q < 8; ++q) a[q] = fmaf(vv[j], (float)p[j][q], a[q]);
            }
        }
        #pragma unroll
        for (int q = 0; q < 8; ++q) a[q] += __shfl_xor(a[q], 32);
        if (par == 0) {
            f16x8 o;
            #pragma unroll
            for (int q = 0; q < 8; ++q) o[q] = (_Float16)fmaxf(a[q], 0.f);
            *(f16x8*)&hl[fl][wid * 4 + i][0] = o;
        }
    }
    __syncthreads();

    // MFMA epilogue: out[16 nodes][64]; wave wid covers cols wid*16..wid*16+15
    const int r  = lane & 15;
    const int kc = lane >> 4;
    f32x4 acc = (f32x4){0.f, 0.f, 0.f, 0.f};
    #pragma unroll
    for (int kk = 0; kk < 8; ++kk) {
        f16x8 af = *(const f16x8*)&hl[kk * 4 + kc][r][0];                       // A[node r][k]
        f16x8 bf = *(const f16x8*)(w2t + (size_t)(wid * 16 + r) * HID + kk * 32 + kc * 8); // B[k][col r]
        acc = __builtin_amdgcn_mfma_f32_16x16x32_f16(af, bf, acc, 0, 0, 0);
    }
    #pragma unroll
    for (int j = 0; j < 4; ++j) {
        int node = nbase + kc * 4 + j;                    // C row = (lane>>4)*4 + j
        h2[(size_t)node * OUTD + wid * 16 + r] = (_Float16)acc[j];  // C col = lane&15
    }
}

// ---------------- SpMM layer 2: 8-edge parity, f16x8 gathers, masked tail ----------------
// par = lane>>3 picks edge residue mod 8; fl = lane&7 covers features fl*8..fl*8+7.

__global__ __launch_bounds__(256) void spmm64_f16(const int* __restrict__ offs,
                                                  const int2* __restrict__ pairs,
                                                  const _Float16* __restrict__ dense,
                                                  float* __restrict__ out, int n) {
    int node = blockIdx.x * 4 + (threadIdx.x >> 6);
    if (node >= n) return;
    int lane = threadIdx.x & 63;
    int par = lane >> 3;         // 0..7
    int fl  = lane & 7;          // feature octet
    int beg = offs[node], end = offs[node + 1];
    const _Float16* dbase = dense + fl * 8;
    float a[8] = {};
    int k = beg;
    for (; k + 32 <= end; k += 32) {
        int2 pr[4];
        #pragma unroll
        for (int j = 0; j < 4; ++j) pr[j] = pairs[k + 8 * j + par];
        f16x8 p[4];
        #pragma unroll
        for (int j = 0; j < 4; ++j)
            p[j] = *(const f16x8*)(dbase + (size_t)pr[j].x * 64);
        #pragma unroll
        for (int j = 0; j < 4; ++j) {
            float v = __int_as_float(pr[j].y);
            #pragma unroll
            for (int q = 0; q < 8; ++q) a[q] = fmaf(v, (float)p[j][q], a[q]);
        }
    }
    if (k < end) {               // masked tail: remainder 1..31
        int2 pr[4];
        float vv[4];
        #pragma unroll
        for (int j = 0; j < 4; ++j) {
            int idx = k + 8 * j + par;
            int cidx = idx < end ? idx : end - 1;
            pr[j] = pairs[cidx];
            vv[j] = idx < end ? __int_as_float(pr[j].y) : 0.f;
        }
        f16x8 p[4];
        #pragma unroll
        for (int j = 0; j < 4; ++j)
            p[j] = *(const f16x8*)(dbase + (size_t)pr[j].x * 64);
        #pragma unroll
        for (int j = 0; j < 4; ++j) {
            #pragma unroll
            for (int q = 0; q < 8; ++q) a[q] = fmaf(vv[j], (float)p[j][q], a[q]);
        }
    }
    #pragma unroll
    for (int q = 0; q < 8; ++q) {
        a[q] += __shfl_xor(a[q], 8);
        a[q] += __shfl_xor(a[q], 16);
        a[q] += __shfl_xor(a[q], 32);
    }
    if (par == 0) {
        float4 o0 = make_float4(a[0], a[1], a[2], a[3]);
        float4 o1 = make_float4(a[4], a[5], a[6], a[7]);
        *(float4*)(out + (size_t)node * 64 + fl * 8)     = o0;
        *(float4*)(out + (size_t)node * 64 + fl * 8 + 4) = o1;
    }
}

// ---------------- launch ----------------

extern "C" void kernel_launch(void* const* d_in, const int* in_sizes, int n_in,
                              void* d_out, int out_size, void* d_ws, size_t ws_size,
                              hipStream_t stream) {
    const float* x    = (const float*)d_in[0];
    const int*   esrc = (const int*)d_in[1];
    const int*   edst = (const int*)d_in[2];
    const float* eval = (const float*)d_in[3];
    const float* w1   = (const float*)d_in[4];
    const float* w2   = (const float*)d_in[5];
    float* out = (float*)d_out;

    char* ws = (char*)d_ws;
    _Float16* pre     = (_Float16*)(ws + 0);            //  51,200,000 B
    _Float16* h2      = (_Float16*)(ws + 51200000);     //  12,800,000 B
    int2*     pairs   = (int2*)(ws + 64000000);         //  25,600,000 B
    int2*     pairs_t = (int2*)(ws + 89600000);         //  32,112,640 B (196*CAP*8)
    int*      srcs_t  = (int*)(ws + 121712640);         //  16,056,320 B (196*CAP*4)
    int*      cursor  = (int*)(ws + 137768960);         //       1,024 B
    int*      bbase   = (int*)(ws + 137769984);         //       1,024 B
    int*      offs    = (int*)(ws + 137771008);         //     400,128 B
    _Float16* w1t     = (_Float16*)(ws + 138171136);    //     262,144 B
    _Float16* w2t     = (_Float16*)(ws + 138433280);    //      32,768 B

    init_cursor_kernel<<<1, 256, 0, stream>>>(cursor);
    bin_kernel<<<1024, 256, 0, stream>>>(esrc, edst, eval, cursor, srcs_t, pairs_t, NE);
    bucket_scan_kernel<<<1, 256, 0, stream>>>(cursor, bbase, offs);
    csr_kernel<<<NB, 1024, 0, stream>>>(cursor, bbase, srcs_t, pairs_t, offs, pairs);

    transpose_cast2<<<(IN_DIM * HID + HID * OUTD + 255) / 256, 256, 0, stream>>>(w1, w2, w1t, w2t);

    gemm1_f32a<<<(NN + 127) / 128, 256, 0, stream>>>(x, w1t, pre, NN);

    spmm_relu_mm2<<<NN / 16, 256, 0, stream>>>(offs, pairs, pre, w2t, h2, NN);

    spmm64_f16<<<(NN + 3) / 4, 256, 0, stream>>>(offs, pairs, h2, out, NN);
}